// Round 7
// baseline (5543.452 us; speedup 1.0000x reference)
//
#include <hip/hip_runtime.h>

#define WAY   100
#define SHOT  5
#define NQ    15
#define DD    4096
#define N_L   500
#define N_U   1500
#define N_TOT 2000
#define LAMF  10.0f
#define EPSF  1e-6f
#define MAXIT 1000

// ---- workspace layout (float offsets) ----
#define OFF_Z      0u          // Z fp32 2000*4096; labeled half dead after musinit -> Zb bf16 overlay
#define OFF_MEANL  8192000u    // 4096 col sums
#define OFF_MEANU  8196096u    // 4096
#define OFF_SL     8200192u    // 100*4096
#define OFF_MUSA   8609792u    // 112*4096
#define OFF_MUSB   9068544u    // 112*4096
#define OFF_MUSQP  9527296u    // 100*256 per-block musq partials (layout [w][block])
#define OFF_MUSB16 9552896u    // bf16 mus 112*4096 sh = 229376 fl
#define OFF_PTH    9782272u    // bf16 P^T hi 112*1536 sh
#define OFF_PTL    9868288u    // bf16 P^T lo 112*1536 sh
#define OFF_KMAT   9954304u    // 150000 (+pad)
#define OFF_COLS   10104320u   // 3*100*32 = 9600
#define OFF_MISC   10113920u   // [0..2]=err3 [3]=Ksum(f) [4]=gen [5]=ctr [8+32b]=arrive slots
#define OFF_ZUT    10114688u   // bf16 Zu^T hi 4096*1536 sh
#define OFF_ZUTL   11687552u   // bf16 Zu^T lo 4096*1536 sh  -> end 13260416 fl

#define SINK_BLOCKS 16
#define RPB 94                 // rows per sinkhorn block
#define PTS 1536               // P^T / ZuT row stride (shorts)

typedef __attribute__((ext_vector_type(8))) short short8_t;
typedef __attribute__((ext_vector_type(4))) float f32x4;

__device__ __forceinline__ short f2bs(float f) {   // fp32 -> bf16 RNE
  unsigned u = __float_as_uint(f);
  unsigned r = (u + 0x7FFFu + ((u >> 16) & 1u)) >> 16;
  return (short)r;
}
__device__ __forceinline__ float bs2f(short s) {
  return __uint_as_float(((unsigned)(unsigned short)s) << 16);
}

// ---------------- preprocessing ----------------
__global__ __launch_bounds__(256) void k_pow_norm(const float* __restrict__ X, float* __restrict__ Z,
                                                  float* __restrict__ msums, unsigned* __restrict__ misc_u) {
  int i = blockIdx.x, tid = threadIdx.x;
  __shared__ float red[256];
  if (i < 32) msums[i * 256 + tid] = 0.f;
  if (i == 32) { misc_u[tid] = 0u; misc_u[tid + 256] = 0u; misc_u[tid + 512] = 0u; }
  const float* x = X + (size_t)i * DD;
  float s = 0.f;
  for (int k = tid; k < DD; k += 256) s += x[k] + 1e-6f;
  red[tid] = s; __syncthreads();
  for (int o = 128; o > 0; o >>= 1) { if (tid < o) red[tid] += red[tid + o]; __syncthreads(); }
  float inv = 1.0f / fmaxf(sqrtf(red[0]), 1e-12f);
  float* z = Z + (size_t)i * DD;
  for (int k = tid; k < DD; k += 256) z[k] = sqrtf(x[k] + 1e-6f) * inv;
}

__global__ __launch_bounds__(256) void k_colmeans(const float* __restrict__ Z, float* __restrict__ mLs,
                                                  float* __restrict__ mUs) {
  int k = blockIdx.x * 256 + threadIdx.x;
  int r0 = blockIdx.y * 80;
  float sL = 0.f, sU = 0.f;
  for (int r = r0; r < r0 + 80; ++r) {
    float v = Z[(size_t)r * DD + k];
    if (r < N_L) sL += v; else sU += v;
  }
  if (r0 < N_L) atomicAdd(&mLs[k], sL);
  if (r0 + 80 > N_L) atomicAdd(&mUs[k], sU);
}

__global__ __launch_bounds__(256) void k_center(float* __restrict__ Z, const float* __restrict__ mLs,
                                                const float* __restrict__ mUs) {
  int i = blockIdx.x, tid = threadIdx.x;
  __shared__ float red[256];
  const float* m = (i < N_L) ? mLs : mUs;
  const float scale = (i < N_L) ? (1.0f / 500.0f) : (1.0f / 1500.0f);
  float* z = Z + (size_t)i * DD;
  float s = 0.f;
  for (int k = tid; k < DD; k += 256) { float v = z[k] - m[k] * scale; s += v * v; }
  red[tid] = s; __syncthreads();
  for (int o = 128; o > 0; o >>= 1) { if (tid < o) red[tid] += red[tid + o]; __syncthreads(); }
  float inv = 1.0f / fmaxf(sqrtf(red[0]), 1e-12f);
  for (int k = tid; k < DD; k += 256) z[k] = (z[k] - m[k] * scale) * inv;
}

__global__ __launch_bounds__(256) void k_musinit(const float* __restrict__ Z, float* __restrict__ SL,
                                                 float* __restrict__ mus, short* __restrict__ musb,
                                                 float* __restrict__ musqP) {
  int w = blockIdx.x, tid = threadIdx.x;
  __shared__ float red[256];
  float q = 0.f;
  for (int k = tid; k < DD; k += 256) {
    float s = 0.f;
    for (int sh = 0; sh < SHOT; ++sh) s += Z[(size_t)(sh * WAY + w) * DD + k];
    SL[(size_t)w * DD + k] = s;
    float m = s / 5.0f;
    mus[(size_t)w * DD + k] = m;
    musb[(size_t)w * DD + k] = f2bs(m);
    q += m * m;
  }
  red[tid] = q; __syncthreads();
  for (int o = 128; o > 0; o >>= 1) { if (tid < o) red[tid] += red[tid + o]; __syncthreads(); }
  if (tid == 0) musqP[(size_t)w * 256] = red[0];
  else musqP[(size_t)w * 256 + tid] = 0.f;
}

// ---- one-time: Zu -> bf16 row-major (rows 1500..1535 zeroed) ----
__global__ __launch_bounds__(256) void k_zb(const float* __restrict__ Z, short* __restrict__ Zb) {
  size_t i0 = ((size_t)blockIdx.x * 256 + threadIdx.x) * 8;
  short8_t v;
  if (i0 < (size_t)N_U * DD) {
    const float* src = Z + (size_t)N_L * DD + i0;
    float4 a = *(const float4*)src;
    float4 b = *(const float4*)(src + 4);
    v[0] = f2bs(a.x); v[1] = f2bs(a.y); v[2] = f2bs(a.z); v[3] = f2bs(a.w);
    v[4] = f2bs(b.x); v[5] = f2bs(b.y); v[6] = f2bs(b.z); v[7] = f2bs(b.w);
  } else {
    v = (short8_t){0, 0, 0, 0, 0, 0, 0, 0};
  }
  *(short8_t*)(Zb + i0) = v;
}

// ---- one-time: Zu^T hi/lo bf16 (4096 x 1536, cols 1500..1535 zeroed) ----
__global__ __launch_bounds__(256) void k_zt(const float* __restrict__ Z, short* __restrict__ ZTH,
                                            short* __restrict__ ZTL) {
  __shared__ float tile[32][33];
  int k0 = blockIdx.x * 32, u0 = blockIdx.y * 32;
  int c = threadIdx.x & 31, r0 = threadIdx.x >> 5;
#pragma unroll
  for (int rr = 0; rr < 4; ++rr) {
    int r = r0 + rr * 8;
    int u = u0 + r;
    tile[r][c] = (u < N_U) ? Z[(size_t)(N_L + u) * DD + k0 + c] : 0.f;
  }
  __syncthreads();
#pragma unroll
  for (int rr = 0; rr < 4; ++rr) {
    int r = r0 + rr * 8;
    float v = tile[c][r];
    short hi = f2bs(v);
    ZTH[(size_t)(k0 + r) * PTS + u0 + c] = hi;
    ZTL[(size_t)(k0 + r) * PTS + u0 + c] = f2bs(v - bs2f(hi));
  }
}

// ---------------- GEMM1+expK fused (MFMA, full K): Kmat[u][w] = exp(-lam*dist) ----------------
// block = 1 wave, u-tile 16, 96 blocks. Prologue reduces musqP; block 0 zeroes sink scratch.
__global__ __launch_bounds__(64) void k_gemm1K(const short* __restrict__ Zb, const short* __restrict__ musb,
                                               const float* __restrict__ musqP, float* __restrict__ Kmat,
                                               float* __restrict__ cols, unsigned* __restrict__ misc_u) {
  int tid = threadIdx.x;
  if (blockIdx.x == 0) {
    for (int z = tid; z < 9600; z += 64) cols[z] = 0.f;
    for (int z = tid; z < 768; z += 64) misc_u[z] = 0u;
  }
  __shared__ float musqL[WAY];
  int l15 = tid & 15, quad = tid >> 4;
  int u0 = blockIdx.x * 16;
  f32x4 acc[7];
#pragma unroll
  for (int c = 0; c < 7; ++c) acc[c] = (f32x4){0.f, 0.f, 0.f, 0.f};

  const short* bp = Zb + (size_t)(u0 + l15) * DD + quad * 8;
  const short* ap = musb + (size_t)l15 * DD + quad * 8;
#pragma unroll 2
  for (int kc = 0; kc < DD; kc += 32) {
    short8_t bf = *(const short8_t*)(bp + kc);
#pragma unroll
    for (int c = 0; c < 7; ++c) {
      short8_t af = *(const short8_t*)(ap + (size_t)c * 16 * DD + kc);
      acc[c] = __builtin_amdgcn_mfma_f32_16x16x32_bf16(af, bf, acc[c], 0, 0, 0);
    }
  }
  for (int w = tid; w < WAY; w += 64) {
    const float* mp = musqP + (size_t)w * 256;
    float q = 0.f;
#pragma unroll 4
    for (int bb = 0; bb < 256; bb += 4) {
      float4 v4 = *(const float4*)(mp + bb);
      q += (v4.x + v4.y) + (v4.z + v4.w);
    }
    musqL[w] = q;
  }
  __syncthreads();
  int u = u0 + l15;
  if (u < N_U) {
#pragma unroll
    for (int c = 0; c < 7; ++c)
#pragma unroll
      for (int r = 0; r < 4; ++r) {
        int w = 16 * c + quad * 4 + r;
        if (w < WAY) {
          float d2 = 1.0f + musqL[w] - 2.0f * acc[c][r];
          Kmat[(size_t)u * WAY + w] = expf(-LAMF * sqrtf(fmaxf(d2, 1e-12f)));
        }
      }
  }
}

// ---------------- sinkhorn (16 blocks, sense-reversing parallel barrier) ----------------
__device__ __forceinline__ void gbar(unsigned* misc_u, unsigned t) {
  __syncthreads();
  if (blockIdx.x == 0) {
    if (threadIdx.x > 0 && threadIdx.x < SINK_BLOCKS) {
      unsigned* slot = misc_u + 8 + threadIdx.x * 32;
      while (__hip_atomic_load(slot, __ATOMIC_ACQUIRE, __HIP_MEMORY_SCOPE_AGENT) < t)
        __builtin_amdgcn_s_sleep(1);
    }
    __syncthreads();
    if (threadIdx.x == 0) {
      __threadfence();
      __hip_atomic_store(misc_u + 4, t, __ATOMIC_RELEASE, __HIP_MEMORY_SCOPE_AGENT);
    }
  } else {
    if (threadIdx.x == 0) {
      __threadfence();
      __hip_atomic_store(misc_u + 8 + (unsigned)blockIdx.x * 32, t, __ATOMIC_RELEASE, __HIP_MEMORY_SCOPE_AGENT);
      while (__hip_atomic_load(misc_u + 4, __ATOMIC_ACQUIRE, __HIP_MEMORY_SCOPE_AGENT) < t)
        __builtin_amdgcn_s_sleep(1);
      __threadfence();
    }
  }
  __syncthreads();
}

__global__ __launch_bounds__(256) void k_sink(const float* __restrict__ Kg,
                                              short* __restrict__ PTH, short* __restrict__ PTL,
                                              float* __restrict__ cols,
                                              unsigned* __restrict__ misc_u, float* __restrict__ misc_f) {
  __shared__ float Kl[RPB * WAY];                // 37.6 KB, 400B rows (16B aligned), proven R3 config
  __shared__ float a[RPB], aold[RPB], prevs[RPB], b[WAY];
  __shared__ float rerr[256];
  __shared__ float c2[2 * WAY];
  __shared__ float red[256];
  unsigned* errG = misc_u;
  float* KsumG = misc_f + 3;
  int tid = threadIdx.x;
  int row0 = blockIdx.x * RPB;
  int nrows = (row0 + RPB <= N_U) ? RPB : (N_U - row0);   // last block: 90

  float ks = 0.f;
  for (int idx = tid; idx < nrows * WAY; idx += 256) { float v = Kg[row0 * WAY + idx]; Kl[idx] = v; ks += v; }
  red[tid] = ks; __syncthreads();
  for (int o = 128; o > 0; o >>= 1) { if (tid < o) red[tid] += red[tid + o]; __syncthreads(); }
  if (tid == 0) atomicAdd(KsumG, red[0]);
  if (tid < RPB) prevs[tid] = 0.f;
  if (tid < WAY) b[tid] = 1.0f;
  unsigned bt = 1;
  gbar(misc_u, bt);
  float S = *KsumG;
  if (tid < RPB) a[tid] = 1.0f / S;       // folds K/K.sum() into a exactly

  bool conv = false;
  for (int t = 0; t < MAXIT; ++t) {
    int buf = t % 3;
    int zb = (t + 1) % 3;
    __syncthreads();
    if (tid < nrows) {
      const float* kr = &Kl[tid * WAY];
      float r0 = 0.f, r1 = 0.f, r2 = 0.f, r3 = 0.f;
#pragma unroll 4
      for (int j = 0; j < WAY; j += 4) {
        r0 = fmaf(kr[j], b[j], r0);
        r1 = fmaf(kr[j + 1], b[j + 1], r1);
        r2 = fmaf(kr[j + 2], b[j + 2], r2);
        r3 = fmaf(kr[j + 3], b[j + 3], r3);
      }
      float rs = ((r0 + r1) + (r2 + r3)) * a[tid];
      rerr[tid] = fabsf(prevs[tid] - rs);
      aold[tid] = a[tid];
      a[tid] = a[tid] / rs;                // speculative; rolled back on convergence
      prevs[tid] = rs;
    } else {
      rerr[tid] = 0.f;
    }
    __syncthreads();
    {
      int j = -1, rlo = 0, rhi = 0, slot = 0;
      if (tid < WAY) { j = tid; rlo = 0; rhi = 47; slot = 0; }
      else if (tid >= 128 && tid < 128 + WAY) { j = tid - 128; rlo = 47; rhi = RPB; slot = 1; }
      if (j >= 0) {
        if (rhi > nrows) rhi = nrows;
        float pc = 0.f;
        for (int r = rlo; r < rhi; ++r) pc = fmaf(Kl[r * WAY + j], a[r], pc);
        c2[slot * WAY + j] = pc;
      }
    }
    __syncthreads();
    if (tid < WAY) atomicAdd(&cols[buf * 3200 + tid * 32], c2[tid] + c2[WAY + tid]);
    if (blockIdx.x == 0) {
      if (tid < WAY) cols[zb * 3200 + tid * 32] = 0.f;   // safe: last read 2 barriers ago
      if (tid == 0) __hip_atomic_store(&errG[zb], 0u, __ATOMIC_RELAXED, __HIP_MEMORY_SCOPE_AGENT);
    }
    if (tid < 64) {
      float m = fmaxf(fmaxf(rerr[tid], rerr[tid + 64]), fmaxf(rerr[tid + 128], rerr[tid + 192]));
#pragma unroll
      for (int o = 32; o > 0; o >>= 1) m = fmaxf(m, __shfl_down(m, o));
      if (tid == 0) atomicMax(&errG[buf], __float_as_uint(m));
    }
    ++bt;
    gbar(misc_u, bt);
    unsigned eu = __hip_atomic_load(&errG[buf], __ATOMIC_RELAXED, __HIP_MEMORY_SCOPE_AGENT);
    if (__uint_as_float(eu) <= EPSF) { conv = true; break; }
    if (tid < WAY) b[tid] = (float)NQ / cols[buf * 3200 + tid * 32];
  }
  __syncthreads();
  // P^T hi/lo bf16 (A-operand for gemm2 + k_final source), coalesced in u
  for (int idx = tid; idx < WAY * nrows; idx += 256) {
    int j = idx / nrows; int r = idx - j * nrows;
    float av = conv ? aold[r] : a[r];
    float p = av * Kl[r * WAY + j] * b[j];
    short hi = f2bs(p);
    PTH[(size_t)j * PTS + row0 + r] = hi;
    PTL[(size_t)j * PTS + row0 + r] = f2bs(p - bs2f(hi));
  }
  if (blockIdx.x == SINK_BLOCKS - 1) {     // zero cols 1500..1503 (gemm2 K loop reads u<1504)
    for (int idx = tid; idx < WAY * 4; idx += 256) {
      int j = idx >> 2;
      PTH[(size_t)j * PTS + 1500 + (idx & 3)] = 0;
      PTL[(size_t)j * PTS + 1500 + (idx & 3)] = 0;
    }
  }
}

// ---------------- GEMM2+musup fused (MFMA, 3-term double-bf16) ----------------
// CP[w][k] = sum_u (Ph+Pl)[w][u] * (Zh+Zl)[k][u]; epilogue does mus update in-register.
__global__ __launch_bounds__(64) void k_gemm2m(const short* __restrict__ PTH, const short* __restrict__ PTL,
                                               const short* __restrict__ ZTH, const short* __restrict__ ZTL,
                                               const float* __restrict__ SL, const float* __restrict__ musR,
                                               float* __restrict__ musW, short* __restrict__ musb,
                                               float* __restrict__ musqP) {
  int tid = threadIdx.x, l15 = tid & 15, quad = tid >> 4;
  int k0 = blockIdx.x * 16;                      // 256 blocks
  f32x4 acc[7];
#pragma unroll
  for (int c = 0; c < 7; ++c) acc[c] = (f32x4){0.f, 0.f, 0.f, 0.f};
  size_t aoff = (size_t)l15 * PTS + quad * 8;
  const short* bph = ZTH + (size_t)(k0 + l15) * PTS + quad * 8;
  const short* bpl = ZTL + (size_t)(k0 + l15) * PTS + quad * 8;
#pragma unroll 1
  for (int kc = 0; kc < 1504; kc += 32) {
    short8_t bh = *(const short8_t*)(bph + kc);
    short8_t bl = *(const short8_t*)(bpl + kc);
#pragma unroll
    for (int c = 0; c < 7; ++c) {
      short8_t ah = *(const short8_t*)(PTH + aoff + (size_t)c * 16 * PTS + kc);
      short8_t al = *(const short8_t*)(PTL + aoff + (size_t)c * 16 * PTS + kc);
      acc[c] = __builtin_amdgcn_mfma_f32_16x16x32_bf16(ah, bh, acc[c], 0, 0, 0);
      acc[c] = __builtin_amdgcn_mfma_f32_16x16x32_bf16(al, bh, acc[c], 0, 0, 0);
      acc[c] = __builtin_amdgcn_mfma_f32_16x16x32_bf16(ah, bl, acc[c], 0, 0, 0);
    }
  }
  int k = k0 + l15;
#pragma unroll
  for (int c = 0; c < 7; ++c)
#pragma unroll
    for (int r = 0; r < 4; ++r) {
      int w = 16 * c + quad * 4 + r;
      if (w < WAY) {                              // uniform within each 16-lane group
        size_t o = (size_t)w * DD + k;
        float emus = (SL[o] + acc[c][r]) / 20.0f; // p.sum(0) == 5 + 15 exactly
        float m = musR[o];
        float v = m + 0.2f * (emus - m);
        musW[o] = v;
        musb[o] = f2bs(v);
        float q = v * v;
        q += __shfl_xor(q, 1); q += __shfl_xor(q, 2);
        q += __shfl_xor(q, 4); q += __shfl_xor(q, 8);
        if (l15 == 0) musqP[(size_t)w * 256 + blockIdx.x] = q;
      }
    }
}

// ---------------- final logP + acc (P reconstructed from hi+lo) ----------------
__global__ __launch_bounds__(128) void k_final(const short* __restrict__ PTH, const short* __restrict__ PTL,
                                               const int* __restrict__ labels, float* __restrict__ out,
                                               unsigned* __restrict__ ctr) {
  int u = blockIdx.x, tid = threadIdx.x;
  __shared__ float vals[WAY];
  if (tid < WAY) {
    float v = bs2f(PTH[(size_t)tid * PTS + u]) + bs2f(PTL[(size_t)tid * PTS + u]);
    vals[tid] = v;
    out[(size_t)u * WAY + tid] = logf(v + 1e-5f);
  }
  __syncthreads();
  if (tid == 0) {
    int am = 0; float bv = vals[0];
    for (int j = 1; j < WAY; ++j) { if (vals[j] > bv) { bv = vals[j]; am = j; } }
    if (am == labels[N_L + u]) atomicAdd(ctr, 1u);
  }
}

__global__ void k_acc(const unsigned* __restrict__ ctr, float* __restrict__ out) {
  if (threadIdx.x == 0) out[N_U * WAY] = (float)(*ctr) / 1500.0f;
}

// ---------------- host ----------------
extern "C" void kernel_launch(void* const* d_in, const int* in_sizes, int n_in,
                              void* d_out, int out_size, void* d_ws, size_t ws_size,
                              hipStream_t stream) {
  const float* X = (const float*)d_in[0];
  const int* labels = (const int*)d_in[1];
  float* out = (float*)d_out;
  float* ws = (float*)d_ws;

  float* Z     = ws + OFF_Z;
  short* Zb    = (short*)(ws + OFF_Z);       // overlays labeled Z rows (dead after musinit)
  float* meanL = ws + OFF_MEANL;
  float* meanU = ws + OFF_MEANU;
  float* SL    = ws + OFF_SL;
  float* musA  = ws + OFF_MUSA;
  float* musB  = ws + OFF_MUSB;
  float* musqP = ws + OFF_MUSQP;
  short* musb16 = (short*)(ws + OFF_MUSB16);
  short* PTH   = (short*)(ws + OFF_PTH);
  short* PTL   = (short*)(ws + OFF_PTL);
  float* Kmat  = ws + OFF_KMAT;
  float* cols  = ws + OFF_COLS;
  float* misc_f = ws + OFF_MISC;
  unsigned* misc_u = (unsigned*)(ws + OFF_MISC);
  short* ZTH   = (short*)(ws + OFF_ZUT);
  short* ZTL   = (short*)(ws + OFF_ZUTL);

  k_pow_norm<<<N_TOT, 256, 0, stream>>>(X, Z, meanL, misc_u);
  k_colmeans<<<dim3(16, 25), 256, 0, stream>>>(Z, meanL, meanU);
  k_center<<<N_TOT, 256, 0, stream>>>(Z, meanL, meanU);
  k_musinit<<<WAY, 256, 0, stream>>>(Z, SL, musA, musb16, musqP);
  k_zt<<<dim3(128, 48), 256, 0, stream>>>(Z, ZTH, ZTL);
  k_zb<<<3072, 256, 0, stream>>>(Z, Zb);     // after k_zt (k_zt reads fp32 Z; Zb overlays Z[0:500])

  float* musR = musA;
  float* musW = musB;
  for (int e = 0; e < 20; ++e) {
    k_gemm1K<<<96, 64, 0, stream>>>(Zb, musb16, musqP, Kmat, cols, misc_u);
    k_sink<<<SINK_BLOCKS, 256, 0, stream>>>(Kmat, PTH, PTL, cols, misc_u, misc_f);
    k_gemm2m<<<256, 64, 0, stream>>>(PTH, PTL, ZTH, ZTL, SL, musR, musW, musb16, musqP);
    float* tmp = musR; musR = musW; musW = tmp;
  }
  k_gemm1K<<<96, 64, 0, stream>>>(Zb, musb16, musqP, Kmat, cols, misc_u);
  k_sink<<<SINK_BLOCKS, 256, 0, stream>>>(Kmat, PTH, PTL, cols, misc_u, misc_f);
  k_final<<<N_U, 128, 0, stream>>>(PTH, PTL, labels, out, misc_u + 5);
  k_acc<<<1, 64, 0, stream>>>(misc_u + 5, out);
}

// Round 8
// 2617.241 us; speedup vs baseline: 2.1181x; 2.1181x over previous
//
#include <hip/hip_runtime.h>

#define WAY   100
#define SHOT  5
#define NQ    15
#define DD    4096
#define N_L   500
#define N_U   1500
#define N_TOT 2000
#define LAMF  10.0f
#define EPSF  1e-6f
#define MAXIT 1000

// ---- workspace layout (float offsets) ----
#define OFF_Z      0u          // Z fp32 2000*4096; labeled half dead after musinit -> Zb bf16 overlay
#define OFF_MEANL  8192000u    // 4096 col sums
#define OFF_MEANU  8196096u    // 4096
#define OFF_SL     8200192u    // 100*4096
#define OFF_MUSA   8609792u    // 112*4096
#define OFF_MUSB   9068544u    // 112*4096
#define OFF_MUSQP  9527296u    // 100*256 per-block musq partials (layout [w][block])
#define OFF_MUSB16 9552896u    // bf16 mus 112*4096 sh = 229376 fl
#define OFF_PTH    9782272u    // bf16 P^T hi 112*1536 sh
#define OFF_PTL    9868288u    // bf16 P^T lo 112*1536 sh
#define OFF_KMAT   9954304u    // 150000 (+pad)
#define OFF_COLS   10104320u   // 3*100*32 = 9600
#define OFF_MISC   10113920u   // [0..2]=err3 [3]=Ksum(f) [5]=ctr [8+32b]=barrier slots
#define OFF_ZUT    10114688u   // bf16 Zu^T hi 4096*1536 sh
#define OFF_ZUTL   11687552u   // bf16 Zu^T lo 4096*1536 sh  -> end 13260416 fl

#define SINK_BLOCKS 16
#define RPB 94                 // rows per sinkhorn block
#define PTS 1536               // P^T / ZuT row stride (shorts)

typedef __attribute__((ext_vector_type(8))) short short8_t;
typedef __attribute__((ext_vector_type(4))) float f32x4;

__device__ __forceinline__ short f2bs(float f) {   // fp32 -> bf16 RNE
  unsigned u = __float_as_uint(f);
  unsigned r = (u + 0x7FFFu + ((u >> 16) & 1u)) >> 16;
  return (short)r;
}
__device__ __forceinline__ float bs2f(short s) {
  return __uint_as_float(((unsigned)(unsigned short)s) << 16);
}

// ---------------- preprocessing ----------------
__global__ __launch_bounds__(256) void k_pow_norm(const float* __restrict__ X, float* __restrict__ Z,
                                                  float* __restrict__ msums, unsigned* __restrict__ misc_u) {
  int i = blockIdx.x, tid = threadIdx.x;
  __shared__ float red[256];
  if (i < 32) msums[i * 256 + tid] = 0.f;
  if (i == 32) { misc_u[tid] = 0u; misc_u[tid + 256] = 0u; misc_u[tid + 512] = 0u; }
  const float* x = X + (size_t)i * DD;
  float s = 0.f;
  for (int k = tid; k < DD; k += 256) s += x[k] + 1e-6f;
  red[tid] = s; __syncthreads();
  for (int o = 128; o > 0; o >>= 1) { if (tid < o) red[tid] += red[tid + o]; __syncthreads(); }
  float inv = 1.0f / fmaxf(sqrtf(red[0]), 1e-12f);
  float* z = Z + (size_t)i * DD;
  for (int k = tid; k < DD; k += 256) z[k] = sqrtf(x[k] + 1e-6f) * inv;
}

__global__ __launch_bounds__(256) void k_colmeans(const float* __restrict__ Z, float* __restrict__ mLs,
                                                  float* __restrict__ mUs) {
  int k = blockIdx.x * 256 + threadIdx.x;
  int r0 = blockIdx.y * 80;
  float sL = 0.f, sU = 0.f;
  for (int r = r0; r < r0 + 80; ++r) {
    float v = Z[(size_t)r * DD + k];
    if (r < N_L) sL += v; else sU += v;
  }
  if (r0 < N_L) atomicAdd(&mLs[k], sL);
  if (r0 + 80 > N_L) atomicAdd(&mUs[k], sU);
}

__global__ __launch_bounds__(256) void k_center(float* __restrict__ Z, const float* __restrict__ mLs,
                                                const float* __restrict__ mUs) {
  int i = blockIdx.x, tid = threadIdx.x;
  __shared__ float red[256];
  const float* m = (i < N_L) ? mLs : mUs;
  const float scale = (i < N_L) ? (1.0f / 500.0f) : (1.0f / 1500.0f);
  float* z = Z + (size_t)i * DD;
  float s = 0.f;
  for (int k = tid; k < DD; k += 256) { float v = z[k] - m[k] * scale; s += v * v; }
  red[tid] = s; __syncthreads();
  for (int o = 128; o > 0; o >>= 1) { if (tid < o) red[tid] += red[tid + o]; __syncthreads(); }
  float inv = 1.0f / fmaxf(sqrtf(red[0]), 1e-12f);
  for (int k = tid; k < DD; k += 256) z[k] = (z[k] - m[k] * scale) * inv;
}

__global__ __launch_bounds__(256) void k_musinit(const float* __restrict__ Z, float* __restrict__ SL,
                                                 float* __restrict__ mus, short* __restrict__ musb,
                                                 float* __restrict__ musqP) {
  int w = blockIdx.x, tid = threadIdx.x;
  __shared__ float red[256];
  float q = 0.f;
  for (int k = tid; k < DD; k += 256) {
    float s = 0.f;
    for (int sh = 0; sh < SHOT; ++sh) s += Z[(size_t)(sh * WAY + w) * DD + k];
    SL[(size_t)w * DD + k] = s;
    float m = s / 5.0f;
    mus[(size_t)w * DD + k] = m;
    musb[(size_t)w * DD + k] = f2bs(m);
    q += m * m;
  }
  red[tid] = q; __syncthreads();
  for (int o = 128; o > 0; o >>= 1) { if (tid < o) red[tid] += red[tid + o]; __syncthreads(); }
  if (tid == 0) musqP[(size_t)w * 256] = red[0];
  else musqP[(size_t)w * 256 + tid] = 0.f;
}

// ---- one-time: Zu -> bf16 row-major (rows 1500..1535 zeroed) ----
__global__ __launch_bounds__(256) void k_zb(const float* __restrict__ Z, short* __restrict__ Zb) {
  size_t i0 = ((size_t)blockIdx.x * 256 + threadIdx.x) * 8;
  short8_t v;
  if (i0 < (size_t)N_U * DD) {
    const float* src = Z + (size_t)N_L * DD + i0;
    float4 a = *(const float4*)src;
    float4 b = *(const float4*)(src + 4);
    v[0] = f2bs(a.x); v[1] = f2bs(a.y); v[2] = f2bs(a.z); v[3] = f2bs(a.w);
    v[4] = f2bs(b.x); v[5] = f2bs(b.y); v[6] = f2bs(b.z); v[7] = f2bs(b.w);
  } else {
    v = (short8_t){0, 0, 0, 0, 0, 0, 0, 0};
  }
  *(short8_t*)(Zb + i0) = v;
}

// ---- one-time: Zu^T hi/lo bf16 (4096 x 1536, cols 1500..1535 zeroed) ----
__global__ __launch_bounds__(256) void k_zt(const float* __restrict__ Z, short* __restrict__ ZTH,
                                            short* __restrict__ ZTL) {
  __shared__ float tile[32][33];
  int k0 = blockIdx.x * 32, u0 = blockIdx.y * 32;
  int c = threadIdx.x & 31, r0 = threadIdx.x >> 5;
#pragma unroll
  for (int rr = 0; rr < 4; ++rr) {
    int r = r0 + rr * 8;
    int u = u0 + r;
    tile[r][c] = (u < N_U) ? Z[(size_t)(N_L + u) * DD + k0 + c] : 0.f;
  }
  __syncthreads();
#pragma unroll
  for (int rr = 0; rr < 4; ++rr) {
    int r = r0 + rr * 8;
    float v = tile[c][r];
    short hi = f2bs(v);
    ZTH[(size_t)(k0 + r) * PTS + u0 + c] = hi;
    ZTL[(size_t)(k0 + r) * PTS + u0 + c] = f2bs(v - bs2f(hi));
  }
}

// ---------------- GEMM1+expK fused (MFMA, 4-wave k-split): Kmat[u][w] = exp(-lam*dist) ------------
__global__ __launch_bounds__(256) void k_gemm1K(const short* __restrict__ Zb, const short* __restrict__ musb,
                                                const float* __restrict__ musqP, float* __restrict__ Kmat,
                                                float* __restrict__ cols, unsigned* __restrict__ misc_u) {
  int tid = threadIdx.x;
  __shared__ float redA[4 * 7 * 4 * 64];   // [wv][c][r][lane] = 28 KB
  __shared__ float musq2[2][128];
  if (blockIdx.x == 0) {
    for (int z = tid; z < 9600; z += 256) cols[z] = 0.f;
    for (int z = tid; z < 768; z += 256) misc_u[z] = 0u;
  }
  // musq reduce: 200 threads, 2 partials per w
  {
    int w = tid >> 1, half = tid & 1;
    float q = 0.f;
    if (w < WAY) {
      const float* mp = musqP + (size_t)w * 256 + half * 128;
#pragma unroll 4
      for (int bb = 0; bb < 128; bb += 4) {
        float4 v4 = *(const float4*)(mp + bb);
        q += (v4.x + v4.y) + (v4.z + v4.w);
      }
      musq2[half][w] = q;
    }
  }
  int wv = tid >> 6, l = tid & 63;
  int l15 = l & 15, quad = (l >> 4) & 3;
  int u0 = blockIdx.x * 16;
  f32x4 acc[7];
#pragma unroll
  for (int c = 0; c < 7; ++c) acc[c] = (f32x4){0.f, 0.f, 0.f, 0.f};

  const short* bp = Zb + (size_t)(u0 + l15) * DD + wv * 1024 + quad * 8;
  const short* ap = musb + (size_t)l15 * DD + wv * 1024 + quad * 8;
#pragma unroll 2
  for (int kc = 0; kc < 1024; kc += 32) {
    short8_t bf = *(const short8_t*)(bp + kc);
#pragma unroll
    for (int c = 0; c < 7; ++c) {
      short8_t af = *(const short8_t*)(ap + (size_t)c * 16 * DD + kc);
      acc[c] = __builtin_amdgcn_mfma_f32_16x16x32_bf16(af, bf, acc[c], 0, 0, 0);
    }
  }
#pragma unroll
  for (int c = 0; c < 7; ++c)
#pragma unroll
    for (int r = 0; r < 4; ++r)
      redA[((wv * 7 + c) * 4 + r) * 64 + l] = acc[c][r];
  __syncthreads();
  if (wv == 0) {
    int u = u0 + l15;
#pragma unroll
    for (int c = 0; c < 7; ++c)
#pragma unroll
      for (int r = 0; r < 4; ++r) {
        int base = (c * 4 + r) * 64 + l;
        float s = redA[base] + redA[base + 1792] + redA[base + 3584] + redA[base + 5376];
        int w = 16 * c + quad * 4 + r;
        if (w < WAY && u < N_U) {
          float d2 = 1.0f + (musq2[0][w] + musq2[1][w]) - 2.0f * s;
          Kmat[(size_t)u * WAY + w] = expf(-LAMF * sqrtf(fmaxf(d2, 1e-12f)));
        }
      }
  }
}

// ---------------- sinkhorn (16 blocks, symmetric barrier) ----------------
__device__ __forceinline__ void gbar(unsigned* slots, unsigned t) {
  __syncthreads();
  if (threadIdx.x == 0) {
    __threadfence();
    __hip_atomic_store(slots + (unsigned)blockIdx.x * 32, t, __ATOMIC_RELEASE, __HIP_MEMORY_SCOPE_AGENT);
  }
  if (threadIdx.x < SINK_BLOCKS) {
    while (__hip_atomic_load(slots + threadIdx.x * 32, __ATOMIC_ACQUIRE, __HIP_MEMORY_SCOPE_AGENT) < t)
      __builtin_amdgcn_s_sleep(1);
  }
  __syncthreads();
}

__global__ __launch_bounds__(256) void k_sink(const float* __restrict__ Kg,
                                              short* __restrict__ PTH, short* __restrict__ PTL,
                                              float* __restrict__ cols,
                                              unsigned* __restrict__ misc_u, float* __restrict__ misc_f) {
  __shared__ float Kl[RPB * WAY];                // 37.6 KB, 400B rows, proven R3 config
  __shared__ float a[RPB], aold[RPB], prevs[RPB], b[WAY];
  __shared__ float rerr[256];
  __shared__ float c2[2 * WAY];
  __shared__ float red[256];
  unsigned* errG = misc_u;
  unsigned* slots = misc_u + 8;
  float* KsumG = misc_f + 3;
  int tid = threadIdx.x;
  int row0 = blockIdx.x * RPB;
  int nrows = (row0 + RPB <= N_U) ? RPB : (N_U - row0);   // last block: 90

  float ks = 0.f;
  for (int idx = tid; idx < nrows * WAY; idx += 256) { float v = Kg[row0 * WAY + idx]; Kl[idx] = v; ks += v; }
  red[tid] = ks; __syncthreads();
  for (int o = 128; o > 0; o >>= 1) { if (tid < o) red[tid] += red[tid + o]; __syncthreads(); }
  if (tid == 0) atomicAdd(KsumG, red[0]);
  if (tid < RPB) prevs[tid] = 0.f;
  if (tid < WAY) b[tid] = 1.0f;
  unsigned bt = 1;
  gbar(slots, bt);
  float S = *KsumG;
  if (tid < RPB) a[tid] = 1.0f / S;       // folds K/K.sum() into a exactly

  bool conv = false;
  for (int t = 0; t < MAXIT; ++t) {
    int buf = t % 3;
    int zb = (t + 1) % 3;
    __syncthreads();
    if (tid < nrows) {
      const float* kr = &Kl[tid * WAY];
      float r0 = 0.f, r1 = 0.f, r2 = 0.f, r3 = 0.f;
#pragma unroll 4
      for (int j = 0; j < WAY; j += 4) {
        r0 = fmaf(kr[j], b[j], r0);
        r1 = fmaf(kr[j + 1], b[j + 1], r1);
        r2 = fmaf(kr[j + 2], b[j + 2], r2);
        r3 = fmaf(kr[j + 3], b[j + 3], r3);
      }
      float rs = ((r0 + r1) + (r2 + r3)) * a[tid];
      rerr[tid] = fabsf(prevs[tid] - rs);
      aold[tid] = a[tid];
      a[tid] = a[tid] / rs;                // speculative; rolled back on convergence
      prevs[tid] = rs;
    } else {
      rerr[tid] = 0.f;
    }
    __syncthreads();
    {
      int j = -1, rlo = 0, rhi = 0, slot = 0;
      if (tid < WAY) { j = tid; rlo = 0; rhi = 47; slot = 0; }
      else if (tid >= 128 && tid < 128 + WAY) { j = tid - 128; rlo = 47; rhi = RPB; slot = 1; }
      if (j >= 0) {
        if (rhi > nrows) rhi = nrows;
        float pc = 0.f;
        for (int r = rlo; r < rhi; ++r) pc = fmaf(Kl[r * WAY + j], a[r], pc);
        c2[slot * WAY + j] = pc;
      }
    }
    __syncthreads();
    if (tid < WAY) atomicAdd(&cols[buf * 3200 + tid * 32], c2[tid] + c2[WAY + tid]);
    if (blockIdx.x == 0) {
      if (tid < WAY) cols[zb * 3200 + tid * 32] = 0.f;   // safe: last read 2 barriers ago
      if (tid == 0) __hip_atomic_store(&errG[zb], 0u, __ATOMIC_RELAXED, __HIP_MEMORY_SCOPE_AGENT);
    }
    if (tid < 64) {
      float m = fmaxf(fmaxf(rerr[tid], rerr[tid + 64]), fmaxf(rerr[tid + 128], rerr[tid + 192]));
#pragma unroll
      for (int o = 32; o > 0; o >>= 1) m = fmaxf(m, __shfl_down(m, o));
      if (tid == 0) atomicMax(&errG[buf], __float_as_uint(m));
    }
    ++bt;
    gbar(slots, bt);
    unsigned eu = __hip_atomic_load(&errG[buf], __ATOMIC_RELAXED, __HIP_MEMORY_SCOPE_AGENT);
    if (__uint_as_float(eu) <= EPSF) { conv = true; break; }
    if (tid < WAY) b[tid] = (float)NQ / cols[buf * 3200 + tid * 32];
  }
  __syncthreads();
  // P^T hi/lo bf16 (A-operand for gemm2 + k_final source), coalesced in u
  for (int idx = tid; idx < WAY * nrows; idx += 256) {
    int j = idx / nrows; int r = idx - j * nrows;
    float av = conv ? aold[r] : a[r];
    float p = av * Kl[r * WAY + j] * b[j];
    short hi = f2bs(p);
    PTH[(size_t)j * PTS + row0 + r] = hi;
    PTL[(size_t)j * PTS + row0 + r] = f2bs(p - bs2f(hi));
  }
  if (blockIdx.x == SINK_BLOCKS - 1) {     // zero cols 1500..1503 (gemm2 K loop reads u<1504)
    for (int idx = tid; idx < WAY * 4; idx += 256) {
      int j = idx >> 2;
      PTH[(size_t)j * PTS + 1500 + (idx & 3)] = 0;
      PTL[(size_t)j * PTS + 1500 + (idx & 3)] = 0;
    }
  }
}

// ---------------- GEMM2+musup fused (MFMA, 3-term, 4-wave u-split) ----------------
__global__ __launch_bounds__(256) void k_gemm2m(const short* __restrict__ PTH, const short* __restrict__ PTL,
                                                const short* __restrict__ ZTH, const short* __restrict__ ZTL,
                                                const float* __restrict__ SL, const float* __restrict__ musR,
                                                float* __restrict__ musW, short* __restrict__ musb,
                                                float* __restrict__ musqP) {
  int tid = threadIdx.x;
  __shared__ float redA[4 * 7 * 4 * 64];   // 28 KB
  int wv = tid >> 6, l = tid & 63;
  int l15 = l & 15, quad = (l >> 4) & 3;
  int k0 = blockIdx.x * 16;                      // 256 blocks
  int kcb = wv * 384;
  int kce = (kcb + 384 < 1504) ? kcb + 384 : 1504;
  f32x4 acc[7];
#pragma unroll
  for (int c = 0; c < 7; ++c) acc[c] = (f32x4){0.f, 0.f, 0.f, 0.f};
  size_t aoff = (size_t)l15 * PTS + quad * 8;
  const short* bph = ZTH + (size_t)(k0 + l15) * PTS + quad * 8;
  const short* bpl = ZTL + (size_t)(k0 + l15) * PTS + quad * 8;
  for (int kc = kcb; kc < kce; kc += 32) {
    short8_t bh = *(const short8_t*)(bph + kc);
    short8_t bl = *(const short8_t*)(bpl + kc);
#pragma unroll
    for (int c = 0; c < 7; ++c) {
      short8_t ah = *(const short8_t*)(PTH + aoff + (size_t)c * 16 * PTS + kc);
      short8_t al = *(const short8_t*)(PTL + aoff + (size_t)c * 16 * PTS + kc);
      acc[c] = __builtin_amdgcn_mfma_f32_16x16x32_bf16(ah, bh, acc[c], 0, 0, 0);
      acc[c] = __builtin_amdgcn_mfma_f32_16x16x32_bf16(al, bh, acc[c], 0, 0, 0);
      acc[c] = __builtin_amdgcn_mfma_f32_16x16x32_bf16(ah, bl, acc[c], 0, 0, 0);
    }
  }
#pragma unroll
  for (int c = 0; c < 7; ++c)
#pragma unroll
    for (int r = 0; r < 4; ++r)
      redA[((wv * 7 + c) * 4 + r) * 64 + l] = acc[c][r];
  __syncthreads();
  if (wv == 0) {
    int k = k0 + l15;
#pragma unroll
    for (int c = 0; c < 7; ++c)
#pragma unroll
      for (int r = 0; r < 4; ++r) {
        int base = (c * 4 + r) * 64 + l;
        float s = redA[base] + redA[base + 1792] + redA[base + 3584] + redA[base + 5376];
        int w = 16 * c + quad * 4 + r;
        if (w < WAY) {                            // uniform within each 16-lane group
          size_t o = (size_t)w * DD + k;
          float emus = (SL[o] + s) / 20.0f;       // p.sum(0) == 5 + 15 exactly
          float m = musR[o];
          float v = m + 0.2f * (emus - m);
          musW[o] = v;
          musb[o] = f2bs(v);
          float q = v * v;
          q += __shfl_xor(q, 1); q += __shfl_xor(q, 2);
          q += __shfl_xor(q, 4); q += __shfl_xor(q, 8);
          if (l15 == 0) musqP[(size_t)w * 256 + blockIdx.x] = q;
        }
      }
  }
}

// ---------------- final logP + acc (P reconstructed from hi+lo) ----------------
__global__ __launch_bounds__(128) void k_final(const short* __restrict__ PTH, const short* __restrict__ PTL,
                                               const int* __restrict__ labels, float* __restrict__ out,
                                               unsigned* __restrict__ ctr) {
  int u = blockIdx.x, tid = threadIdx.x;
  __shared__ float vals[WAY];
  if (tid < WAY) {
    float v = bs2f(PTH[(size_t)tid * PTS + u]) + bs2f(PTL[(size_t)tid * PTS + u]);
    vals[tid] = v;
    out[(size_t)u * WAY + tid] = logf(v + 1e-5f);
  }
  __syncthreads();
  if (tid == 0) {
    int am = 0; float bv = vals[0];
    for (int j = 1; j < WAY; ++j) { if (vals[j] > bv) { bv = vals[j]; am = j; } }
    if (am == labels[N_L + u]) atomicAdd(ctr, 1u);
  }
}

__global__ void k_acc(const unsigned* __restrict__ ctr, float* __restrict__ out) {
  if (threadIdx.x == 0) out[N_U * WAY] = (float)(*ctr) / 1500.0f;
}

// ---------------- host ----------------
extern "C" void kernel_launch(void* const* d_in, const int* in_sizes, int n_in,
                              void* d_out, int out_size, void* d_ws, size_t ws_size,
                              hipStream_t stream) {
  const float* X = (const float*)d_in[0];
  const int* labels = (const int*)d_in[1];
  float* out = (float*)d_out;
  float* ws = (float*)d_ws;

  float* Z     = ws + OFF_Z;
  short* Zb    = (short*)(ws + OFF_Z);       // overlays labeled Z rows (dead after musinit)
  float* meanL = ws + OFF_MEANL;
  float* meanU = ws + OFF_MEANU;
  float* SL    = ws + OFF_SL;
  float* musA  = ws + OFF_MUSA;
  float* musB  = ws + OFF_MUSB;
  float* musqP = ws + OFF_MUSQP;
  short* musb16 = (short*)(ws + OFF_MUSB16);
  short* PTH   = (short*)(ws + OFF_PTH);
  short* PTL   = (short*)(ws + OFF_PTL);
  float* Kmat  = ws + OFF_KMAT;
  float* cols  = ws + OFF_COLS;
  float* misc_f = ws + OFF_MISC;
  unsigned* misc_u = (unsigned*)(ws + OFF_MISC);
  short* ZTH   = (short*)(ws + OFF_ZUT);
  short* ZTL   = (short*)(ws + OFF_ZUTL);

  k_pow_norm<<<N_TOT, 256, 0, stream>>>(X, Z, meanL, misc_u);
  k_colmeans<<<dim3(16, 25), 256, 0, stream>>>(Z, meanL, meanU);
  k_center<<<N_TOT, 256, 0, stream>>>(Z, meanL, meanU);
  k_musinit<<<WAY, 256, 0, stream>>>(Z, SL, musA, musb16, musqP);
  k_zt<<<dim3(128, 48), 256, 0, stream>>>(Z, ZTH, ZTL);
  k_zb<<<3072, 256, 0, stream>>>(Z, Zb);     // after k_zt (k_zt reads fp32 Z; Zb overlays Z[0:500])

  float* musR = musA;
  float* musW = musB;
  for (int e = 0; e < 20; ++e) {
    k_gemm1K<<<96, 256, 0, stream>>>(Zb, musb16, musqP, Kmat, cols, misc_u);
    k_sink<<<SINK_BLOCKS, 256, 0, stream>>>(Kmat, PTH, PTL, cols, misc_u, misc_f);
    k_gemm2m<<<256, 256, 0, stream>>>(PTH, PTL, ZTH, ZTL, SL, musR, musW, musb16, musqP);
    float* tmp = musR; musR = musW; musW = tmp;
  }
  k_gemm1K<<<96, 256, 0, stream>>>(Zb, musb16, musqP, Kmat, cols, misc_u);
  k_sink<<<SINK_BLOCKS, 256, 0, stream>>>(Kmat, PTH, PTL, cols, misc_u, misc_f);
  k_final<<<N_U, 128, 0, stream>>>(PTH, PTL, labels, out, misc_u + 5);
  k_acc<<<1, 64, 0, stream>>>(misc_u + 5, out);
}

// Round 9
// 2412.079 us; speedup vs baseline: 2.2982x; 1.0851x over previous
//
#include <hip/hip_runtime.h>

#define WAY   100
#define SHOT  5
#define NQ    15
#define DD    4096
#define N_L   500
#define N_U   1500
#define N_TOT 2000
#define LAMF  10.0f
#define EPSF  1e-6f
#define MAXIT 1000

// ---- workspace layout (float offsets) ----
#define OFF_Z      0u          // Z fp32 2000*4096. After preproc: Zb bf16 (3145728 fl) at 0,
                               //   CPp (8*409600 fl) at 3145728 (dead fp32 Zu region)
#define OFF_CPP    3145728u
#define OFF_MEANL  8192000u    // 4096 col sums
#define OFF_MEANU  8196096u    // 4096
#define OFF_SL     8200192u    // 100*4096
#define OFF_MUSA   8609792u    // 112*4096
#define OFF_MUSB   9068544u    // 112*4096
#define OFF_MUSQP  9527296u    // 100*256 musq partials [w][0]=value, rest zero
#define OFF_MUSB16 9552896u    // bf16 mus 112*4096 sh = 229376 fl
#define OFF_PTH    9782272u    // bf16 P^T hi 112*1536 sh
#define OFF_PTL    9868288u    // bf16 P^T lo 112*1536 sh
#define OFF_KMAT   9954304u    // 150000 (+pad)
#define OFF_COLS   10104320u   // colsP [2][32][128] = 8192 fl
#define OFF_MISC   10113920u   // [3]=Ksum(f) [5]=ctr [8+16b]=barrier slots (b<32)
#define OFF_ZUT    10114688u   // bf16 Zu^T hi 4096*1536 sh
#define OFF_ZUTL   11687552u   // bf16 Zu^T lo 4096*1536 sh  -> end 13260416 fl

#define SINK_BLOCKS 32
#define RPB 47                 // rows per sinkhorn block (32*47 = 1504)
#define PTS 1536               // P^T / ZuT row stride (shorts)
#define CPS 409600u            // CP partial stride (100*4096)

typedef __attribute__((ext_vector_type(8))) short short8_t;
typedef __attribute__((ext_vector_type(4))) float f32x4;

__device__ __forceinline__ short f2bs(float f) {   // fp32 -> bf16 RNE
  unsigned u = __float_as_uint(f);
  unsigned r = (u + 0x7FFFu + ((u >> 16) & 1u)) >> 16;
  return (short)r;
}
__device__ __forceinline__ float bs2f(short s) {
  return __uint_as_float(((unsigned)(unsigned short)s) << 16);
}

// ---------------- preprocessing ----------------
__global__ __launch_bounds__(256) void k_pow_norm(const float* __restrict__ X, float* __restrict__ Z,
                                                  float* __restrict__ msums, unsigned* __restrict__ misc_u) {
  int i = blockIdx.x, tid = threadIdx.x;
  __shared__ float red[256];
  if (i < 32) msums[i * 256 + tid] = 0.f;
  if (i == 32) { misc_u[tid] = 0u; misc_u[tid + 256] = 0u; misc_u[tid + 512] = 0u; }
  const float* x = X + (size_t)i * DD;
  float s = 0.f;
  for (int k = tid; k < DD; k += 256) s += x[k] + 1e-6f;
  red[tid] = s; __syncthreads();
  for (int o = 128; o > 0; o >>= 1) { if (tid < o) red[tid] += red[tid + o]; __syncthreads(); }
  float inv = 1.0f / fmaxf(sqrtf(red[0]), 1e-12f);
  float* z = Z + (size_t)i * DD;
  for (int k = tid; k < DD; k += 256) z[k] = sqrtf(x[k] + 1e-6f) * inv;
}

__global__ __launch_bounds__(256) void k_colmeans(const float* __restrict__ Z, float* __restrict__ mLs,
                                                  float* __restrict__ mUs) {
  int k = blockIdx.x * 256 + threadIdx.x;
  int r0 = blockIdx.y * 80;
  float sL = 0.f, sU = 0.f;
  for (int r = r0; r < r0 + 80; ++r) {
    float v = Z[(size_t)r * DD + k];
    if (r < N_L) sL += v; else sU += v;
  }
  if (r0 < N_L) atomicAdd(&mLs[k], sL);
  if (r0 + 80 > N_L) atomicAdd(&mUs[k], sU);
}

__global__ __launch_bounds__(256) void k_center(float* __restrict__ Z, const float* __restrict__ mLs,
                                                const float* __restrict__ mUs) {
  int i = blockIdx.x, tid = threadIdx.x;
  __shared__ float red[256];
  const float* m = (i < N_L) ? mLs : mUs;
  const float scale = (i < N_L) ? (1.0f / 500.0f) : (1.0f / 1500.0f);
  float* z = Z + (size_t)i * DD;
  float s = 0.f;
  for (int k = tid; k < DD; k += 256) { float v = z[k] - m[k] * scale; s += v * v; }
  red[tid] = s; __syncthreads();
  for (int o = 128; o > 0; o >>= 1) { if (tid < o) red[tid] += red[tid + o]; __syncthreads(); }
  float inv = 1.0f / fmaxf(sqrtf(red[0]), 1e-12f);
  for (int k = tid; k < DD; k += 256) z[k] = (z[k] - m[k] * scale) * inv;
}

__global__ __launch_bounds__(256) void k_musinit(const float* __restrict__ Z, float* __restrict__ SL,
                                                 float* __restrict__ mus, short* __restrict__ musb,
                                                 float* __restrict__ musqP) {
  int w = blockIdx.x, tid = threadIdx.x;
  __shared__ float red[256];
  float q = 0.f;
  for (int k = tid; k < DD; k += 256) {
    float s = 0.f;
    for (int sh = 0; sh < SHOT; ++sh) s += Z[(size_t)(sh * WAY + w) * DD + k];
    SL[(size_t)w * DD + k] = s;
    float m = s / 5.0f;
    mus[(size_t)w * DD + k] = m;
    musb[(size_t)w * DD + k] = f2bs(m);
    q += m * m;
  }
  red[tid] = q; __syncthreads();
  for (int o = 128; o > 0; o >>= 1) { if (tid < o) red[tid] += red[tid + o]; __syncthreads(); }
  if (tid == 0) musqP[(size_t)w * 256] = red[0];
  else musqP[(size_t)w * 256 + tid] = 0.f;
}

// ---- one-time: Zu -> bf16 row-major; launched twice (ubase 0 then 768) to avoid
//      overlap race: lo half reads rows 500..1267 fp32 while writing fl [0,1.57M)
//      (below all sources); hi half then reads rows 1268+ (its dest overlaps only
//      already-consumed sources). Rows 1500..1535 zeroed. ----
__global__ __launch_bounds__(256) void k_zb(const float* __restrict__ Z, short* __restrict__ Zb, int ubase) {
  size_t i0 = (size_t)ubase * DD + ((size_t)blockIdx.x * 256 + threadIdx.x) * 8;
  short8_t v;
  if (i0 < (size_t)N_U * DD) {
    const float* src = Z + (size_t)N_L * DD + i0;
    float4 a = *(const float4*)src;
    float4 b = *(const float4*)(src + 4);
    v[0] = f2bs(a.x); v[1] = f2bs(a.y); v[2] = f2bs(a.z); v[3] = f2bs(a.w);
    v[4] = f2bs(b.x); v[5] = f2bs(b.y); v[6] = f2bs(b.z); v[7] = f2bs(b.w);
  } else {
    v = (short8_t){0, 0, 0, 0, 0, 0, 0, 0};
  }
  *(short8_t*)(Zb + i0) = v;
}

// ---- one-time: Zu^T hi/lo bf16 (4096 x 1536, cols 1500..1535 zeroed) ----
__global__ __launch_bounds__(256) void k_zt(const float* __restrict__ Z, short* __restrict__ ZTH,
                                            short* __restrict__ ZTL) {
  __shared__ float tile[32][33];
  int k0 = blockIdx.x * 32, u0 = blockIdx.y * 32;
  int c = threadIdx.x & 31, r0 = threadIdx.x >> 5;
#pragma unroll
  for (int rr = 0; rr < 4; ++rr) {
    int r = r0 + rr * 8;
    int u = u0 + r;
    tile[r][c] = (u < N_U) ? Z[(size_t)(N_L + u) * DD + k0 + c] : 0.f;
  }
  __syncthreads();
#pragma unroll
  for (int rr = 0; rr < 4; ++rr) {
    int r = r0 + rr * 8;
    float v = tile[c][r];
    short hi = f2bs(v);
    ZTH[(size_t)(k0 + r) * PTS + u0 + c] = hi;
    ZTL[(size_t)(k0 + r) * PTS + u0 + c] = f2bs(v - bs2f(hi));
  }
}

// ---------------- GEMM1+expK fused (MFMA, 4-wave k-split): Kmat[u][w] = exp(-lam*dist) ------------
__global__ __launch_bounds__(256) void k_gemm1K(const short* __restrict__ Zb, const short* __restrict__ musb,
                                                const float* __restrict__ musqP, float* __restrict__ Kmat,
                                                unsigned* __restrict__ misc_u) {
  int tid = threadIdx.x;
  __shared__ float redA[4 * 7 * 4 * 64];   // 28 KB
  __shared__ float musq2[2][128];
  if (blockIdx.x == 0) {
    for (int z = tid; z < 768; z += 256) misc_u[z] = 0u;   // Ksum + barrier slots (+ctr, pre-final ok)
  }
  {
    int w = tid >> 1, half = tid & 1;
    if (w < WAY) {
      const float* mp = musqP + (size_t)w * 256 + half * 128;
      float q = 0.f;
#pragma unroll 4
      for (int bb = 0; bb < 128; bb += 4) {
        float4 v4 = *(const float4*)(mp + bb);
        q += (v4.x + v4.y) + (v4.z + v4.w);
      }
      musq2[half][w] = q;
    }
  }
  int wv = tid >> 6, l = tid & 63;
  int l15 = l & 15, quad = (l >> 4) & 3;
  int u0 = blockIdx.x * 16;
  f32x4 acc[7];
#pragma unroll
  for (int c = 0; c < 7; ++c) acc[c] = (f32x4){0.f, 0.f, 0.f, 0.f};

  const short* bp = Zb + (size_t)(u0 + l15) * DD + wv * 1024 + quad * 8;
  const short* ap = musb + (size_t)l15 * DD + wv * 1024 + quad * 8;
#pragma unroll 2
  for (int kc = 0; kc < 1024; kc += 32) {
    short8_t bf = *(const short8_t*)(bp + kc);
#pragma unroll
    for (int c = 0; c < 7; ++c) {
      short8_t af = *(const short8_t*)(ap + (size_t)c * 16 * DD + kc);
      acc[c] = __builtin_amdgcn_mfma_f32_16x16x32_bf16(af, bf, acc[c], 0, 0, 0);
    }
  }
#pragma unroll
  for (int c = 0; c < 7; ++c)
#pragma unroll
    for (int r = 0; r < 4; ++r)
      redA[((wv * 7 + c) * 4 + r) * 64 + l] = acc[c][r];
  __syncthreads();
  if (wv == 0) {
    int u = u0 + l15;
#pragma unroll
    for (int c = 0; c < 7; ++c)
#pragma unroll
      for (int r = 0; r < 4; ++r) {
        int base = (c * 4 + r) * 64 + l;
        float s = redA[base] + redA[base + 1792] + redA[base + 3584] + redA[base + 5376];
        int w = 16 * c + quad * 4 + r;
        if (w < WAY && u < N_U) {
          float d2 = 1.0f + (musq2[0][w] + musq2[1][w]) - 2.0f * s;
          Kmat[(size_t)u * WAY + w] = expf(-LAMF * sqrtf(fmaxf(d2, 1e-12f)));
        }
      }
  }
}

// ---------------- sinkhorn (32 blocks, symmetric barrier, atomic-free col exchange) ----------------
__device__ __forceinline__ void gbar(unsigned* slots, unsigned t) {
  __syncthreads();
  if (threadIdx.x == 0) {
    __threadfence();
    __hip_atomic_store(slots + (unsigned)blockIdx.x * 16, t, __ATOMIC_RELEASE, __HIP_MEMORY_SCOPE_AGENT);
  }
  if (threadIdx.x < SINK_BLOCKS) {
    while (__hip_atomic_load(slots + threadIdx.x * 16, __ATOMIC_ACQUIRE, __HIP_MEMORY_SCOPE_AGENT) < t)
      __builtin_amdgcn_s_sleep(1);
  }
  __syncthreads();
}

__global__ __launch_bounds__(256) void k_sink(const float* __restrict__ Kg,
                                              short* __restrict__ PTH, short* __restrict__ PTL,
                                              float* __restrict__ colsP,
                                              unsigned* __restrict__ misc_u, float* __restrict__ misc_f) {
  __shared__ float Kl[RPB * WAY];                // 18.8 KB
  __shared__ float a[RPB], aold[RPB], prevs[RPB], b[WAY];
  __shared__ float rerr[256];
  __shared__ float c2[2 * WAY];
  __shared__ float red[256];
  __shared__ float eSh;
  unsigned* slots = misc_u + 8;
  float* KsumG = misc_f + 3;
  int tid = threadIdx.x;
  int row0 = blockIdx.x * RPB;
  int nrows = (row0 + RPB <= N_U) ? RPB : (N_U - row0);   // last block: 43

  float ks = 0.f;
  for (int idx = tid; idx < nrows * WAY; idx += 256) { float v = Kg[row0 * WAY + idx]; Kl[idx] = v; ks += v; }
  red[tid] = ks; __syncthreads();
  for (int o = 128; o > 0; o >>= 1) { if (tid < o) red[tid] += red[tid + o]; __syncthreads(); }
  if (tid == 0) atomicAdd(KsumG, red[0]);
  if (tid < RPB) prevs[tid] = 0.f;
  if (tid < WAY) b[tid] = 1.0f;
  unsigned bt = 1;
  gbar(slots, bt);
  float S = *KsumG;
  if (tid < RPB) a[tid] = 1.0f / S;       // folds K/K.sum() into a exactly

  bool conv = false;
  for (int t = 0; t < MAXIT; ++t) {
    float* cp = colsP + (t & 1) * 4096;
    __syncthreads();                       // b stable
    if (tid < nrows) {
      const float* kr = &Kl[tid * WAY];
      float r0 = 0.f, r1 = 0.f, r2 = 0.f, r3 = 0.f;
#pragma unroll 4
      for (int j = 0; j < WAY; j += 4) {
        r0 = fmaf(kr[j], b[j], r0);
        r1 = fmaf(kr[j + 1], b[j + 1], r1);
        r2 = fmaf(kr[j + 2], b[j + 2], r2);
        r3 = fmaf(kr[j + 3], b[j + 3], r3);
      }
      float rs = ((r0 + r1) + (r2 + r3)) * a[tid];
      rerr[tid] = fabsf(prevs[tid] - rs);
      aold[tid] = a[tid];
      a[tid] = a[tid] / rs;                // speculative; rolled back on convergence
      prevs[tid] = rs;
    } else {
      rerr[tid] = 0.f;
    }
    __syncthreads();
    {
      int j = -1, rlo = 0, rhi = 0, slot = 0;
      if (tid < WAY) { j = tid; rlo = 0; rhi = 24; slot = 0; }
      else if (tid >= 128 && tid < 128 + WAY) { j = tid - 128; rlo = 24; rhi = RPB; slot = 1; }
      if (j >= 0) {
        if (rhi > nrows) rhi = nrows;
        float pc = 0.f;
        for (int r = rlo; r < rhi; ++r) pc = fmaf(Kl[r * WAY + j], a[r], pc);
        c2[slot * WAY + j] = pc;
      }
    }
    __syncthreads();
    if (tid < WAY) cp[(unsigned)blockIdx.x * 128 + tid] = c2[tid] + c2[WAY + tid];
    if (tid < 64) {
      float m = fmaxf(fmaxf(rerr[tid], rerr[tid + 64]), fmaxf(rerr[tid + 128], rerr[tid + 192]));
#pragma unroll
      for (int o = 32; o > 0; o >>= 1) m = fmaxf(m, __shfl_down(m, o));
      if (tid == 0) cp[(unsigned)blockIdx.x * 128 + 100] = m;
    }
    ++bt;
    gbar(slots, bt);
    if (tid < 64) {                         // lanes 32..63 contribute 0 (errors >= 0)
      float e = (tid < SINK_BLOCKS) ? cp[tid * 128 + 100] : 0.f;
#pragma unroll
      for (int o = 32; o > 0; o >>= 1) e = fmaxf(e, __shfl_down(e, o));
      if (tid == 0) eSh = e;
    }
    __syncthreads();
    if (eSh <= EPSF) { conv = true; break; }
    if (tid < WAY) {
      float s = 0.f;
#pragma unroll 8
      for (int sb = 0; sb < SINK_BLOCKS; ++sb) s += cp[sb * 128 + tid];
      b[tid] = (float)NQ / s;
    }
  }
  __syncthreads();
  // P^T hi/lo bf16 (A-operand for gemm2 + k_final source), coalesced in u
  for (int idx = tid; idx < WAY * nrows; idx += 256) {
    int j = idx / nrows; int r = idx - j * nrows;
    float av = conv ? aold[r] : a[r];
    float p = av * Kl[r * WAY + j] * b[j];
    short hi = f2bs(p);
    PTH[(size_t)j * PTS + row0 + r] = hi;
    PTL[(size_t)j * PTS + row0 + r] = f2bs(p - bs2f(hi));
  }
  if (blockIdx.x == SINK_BLOCKS - 1) {     // zero cols 1500..1503 (gemm2 K loop reads u<1504)
    for (int idx = tid; idx < WAY * 4; idx += 256) {
      int j = idx >> 2;
      PTH[(size_t)j * PTS + 1500 + (idx & 3)] = 0;
      PTL[(size_t)j * PTS + 1500 + (idx & 3)] = 0;
    }
  }
}

// ---------------- GEMM2 (MFMA, 3-term, u-split partials; 2048 waves) ----------------
__global__ __launch_bounds__(64) void k_gemm2(const short* __restrict__ PTH, const short* __restrict__ PTL,
                                              const short* __restrict__ ZTH, const short* __restrict__ ZTL,
                                              float* __restrict__ CPp) {
  int l = threadIdx.x, l15 = l & 15, quad = l >> 4;
  int k0 = blockIdx.x * 16;                      // 256 k-tiles
  int us = blockIdx.y;                           // 8 u-splits
  int kcb = us * 192;
  int kce = (us == 7) ? 1504 : kcb + 192;
  f32x4 acc[7];
#pragma unroll
  for (int c = 0; c < 7; ++c) acc[c] = (f32x4){0.f, 0.f, 0.f, 0.f};
  size_t aoff = (size_t)l15 * PTS + quad * 8;
  const short* bph = ZTH + (size_t)(k0 + l15) * PTS + quad * 8;
  const short* bpl = ZTL + (size_t)(k0 + l15) * PTS + quad * 8;
  for (int kc = kcb; kc < kce; kc += 32) {
    short8_t bh = *(const short8_t*)(bph + kc);
    short8_t bl = *(const short8_t*)(bpl + kc);
#pragma unroll
    for (int c = 0; c < 7; ++c) {
      short8_t ah = *(const short8_t*)(PTH + aoff + (size_t)c * 16 * PTS + kc);
      short8_t al = *(const short8_t*)(PTL + aoff + (size_t)c * 16 * PTS + kc);
      acc[c] = __builtin_amdgcn_mfma_f32_16x16x32_bf16(ah, bh, acc[c], 0, 0, 0);
      acc[c] = __builtin_amdgcn_mfma_f32_16x16x32_bf16(al, bh, acc[c], 0, 0, 0);
      acc[c] = __builtin_amdgcn_mfma_f32_16x16x32_bf16(ah, bl, acc[c], 0, 0, 0);
    }
  }
  float* dst = CPp + (size_t)us * CPS;
#pragma unroll
  for (int c = 0; c < 7; ++c)
#pragma unroll
    for (int r = 0; r < 4; ++r) {
      int w = 16 * c + quad * 4 + r;
      if (w < WAY) dst[(size_t)w * DD + k0 + l15] = acc[c][r];
    }
}

// ---------------- mus update + musq (reduces 8 CP partials) ----------------
__global__ __launch_bounds__(256) void k_musup(const float* __restrict__ musR, const float* __restrict__ SL,
                                               const float* __restrict__ CPp, float* __restrict__ musW,
                                               short* __restrict__ musb, float* __restrict__ musqP) {
  int w = blockIdx.x, tid = threadIdx.x;
  __shared__ float red[256];
  float q = 0.f;
  for (int k = tid; k < DD; k += 256) {
    size_t o = (size_t)w * DD + k;
    float c = 0.f;
#pragma unroll
    for (int s = 0; s < 8; ++s) c += CPp[(size_t)s * CPS + o];
    float emus = (SL[o] + c) / 20.0f;   // p.sum(0) == 5 + 15 exactly
    float m = musR[o];
    float v = m + 0.2f * (emus - m);
    musW[o] = v;
    musb[o] = f2bs(v);
    q += v * v;
  }
  red[tid] = q; __syncthreads();
  for (int o = 128; o > 0; o >>= 1) { if (tid < o) red[tid] += red[tid + o]; __syncthreads(); }
  if (tid == 0) musqP[(size_t)w * 256] = red[0];   // entries 1..255 stay zero (musinit)
}

// ---------------- final logP + acc (P reconstructed from hi+lo) ----------------
__global__ __launch_bounds__(128) void k_final(const short* __restrict__ PTH, const short* __restrict__ PTL,
                                               const int* __restrict__ labels, float* __restrict__ out,
                                               unsigned* __restrict__ ctr) {
  int u = blockIdx.x, tid = threadIdx.x;
  __shared__ float vals[WAY];
  if (tid < WAY) {
    float v = bs2f(PTH[(size_t)tid * PTS + u]) + bs2f(PTL[(size_t)tid * PTS + u]);
    vals[tid] = v;
    out[(size_t)u * WAY + tid] = logf(v + 1e-5f);
  }
  __syncthreads();
  if (tid == 0) {
    int am = 0; float bv = vals[0];
    for (int j = 1; j < WAY; ++j) { if (vals[j] > bv) { bv = vals[j]; am = j; } }
    if (am == labels[N_L + u]) atomicAdd(ctr, 1u);
  }
}

__global__ void k_acc(const unsigned* __restrict__ ctr, float* __restrict__ out) {
  if (threadIdx.x == 0) out[N_U * WAY] = (float)(*ctr) / 1500.0f;
}

// ---------------- host ----------------
extern "C" void kernel_launch(void* const* d_in, const int* in_sizes, int n_in,
                              void* d_out, int out_size, void* d_ws, size_t ws_size,
                              hipStream_t stream) {
  const float* X = (const float*)d_in[0];
  const int* labels = (const int*)d_in[1];
  float* out = (float*)d_out;
  float* ws = (float*)d_ws;

  float* Z     = ws + OFF_Z;
  short* Zb    = (short*)(ws + OFF_Z);       // 3145728 fl, overlays Z rows 0..768 (sequenced via 2 launches)
  float* CPp   = ws + OFF_CPP;               // dead fp32 Zu region after zb
  float* meanL = ws + OFF_MEANL;
  float* meanU = ws + OFF_MEANU;
  float* SL    = ws + OFF_SL;
  float* musA  = ws + OFF_MUSA;
  float* musB  = ws + OFF_MUSB;
  float* musqP = ws + OFF_MUSQP;
  short* musb16 = (short*)(ws + OFF_MUSB16);
  short* PTH   = (short*)(ws + OFF_PTH);
  short* PTL   = (short*)(ws + OFF_PTL);
  float* Kmat  = ws + OFF_KMAT;
  float* colsP = ws + OFF_COLS;
  float* misc_f = ws + OFF_MISC;
  unsigned* misc_u = (unsigned*)(ws + OFF_MISC);
  short* ZTH   = (short*)(ws + OFF_ZUT);
  short* ZTL   = (short*)(ws + OFF_ZUTL);

  k_pow_norm<<<N_TOT, 256, 0, stream>>>(X, Z, meanL, misc_u);
  k_colmeans<<<dim3(16, 25), 256, 0, stream>>>(Z, meanL, meanU);
  k_center<<<N_TOT, 256, 0, stream>>>(Z, meanL, meanU);
  k_musinit<<<WAY, 256, 0, stream>>>(Z, SL, musA, musb16, musqP);
  k_zt<<<dim3(128, 48), 256, 0, stream>>>(Z, ZTH, ZTL);
  k_zb<<<1536, 256, 0, stream>>>(Z, Zb, 0);    // lo half: no src/dst overlap
  k_zb<<<1536, 256, 0, stream>>>(Z, Zb, 768);  // hi half: overlaps only consumed sources

  float* musR = musA;
  float* musW = musB;
  for (int e = 0; e < 20; ++e) {
    k_gemm1K<<<96, 256, 0, stream>>>(Zb, musb16, musqP, Kmat, misc_u);
    k_sink<<<SINK_BLOCKS, 256, 0, stream>>>(Kmat, PTH, PTL, colsP, misc_u, misc_f);
    k_gemm2<<<dim3(256, 8), 64, 0, stream>>>(PTH, PTL, ZTH, ZTL, CPp);
    k_musup<<<WAY, 256, 0, stream>>>(musR, SL, CPp, musW, musb16, musqP);
    float* tmp = musR; musR = musW; musW = tmp;
  }
  k_gemm1K<<<96, 256, 0, stream>>>(Zb, musb16, musqP, Kmat, misc_u);
  k_sink<<<SINK_BLOCKS, 256, 0, stream>>>(Kmat, PTH, PTL, colsP, misc_u, misc_f);
  k_final<<<N_U, 128, 0, stream>>>(PTH, PTL, labels, out, misc_u + 5);
  k_acc<<<1, 64, 0, stream>>>(misc_u + 5, out);
}

// Round 11
// 2270.977 us; speedup vs baseline: 2.4410x; 1.0621x over previous
//
#include <hip/hip_runtime.h>

#define WAY   100
#define SHOT  5
#define NQ    15
#define DD    4096
#define N_L   500
#define N_U   1500
#define N_TOT 2000
#define LAMF  10.0f
#define EPSF  1e-6f
#define MAXIT 1000

// ---- workspace layout (float offsets) ----
#define OFF_Z      0u          // Z fp32 2000*4096. After preproc: Zb bf16 (3145728 fl) at 0,
                               //   CPp (8*409600 fl) at 3145728 (dead fp32 Zu region)
#define OFF_CPP    3145728u
#define OFF_MEANL  8192000u    // 4096 col sums
#define OFF_MEANU  8196096u    // 4096
#define OFF_SL     8200192u    // 100*4096
#define OFF_MUSA   8609792u    // 112*4096
#define OFF_MUSB   9068544u    // 112*4096
#define OFF_MUSQP  9527296u    // 100*256 musq partials [w][0..3] from musup, rest zero
#define OFF_MUSB16 9552896u    // bf16 mus 112*4096 sh = 229376 fl
#define OFF_PTH    9782272u    // bf16 P^T hi 112*1536 sh = 86016 fl
#define OFF_PTL    9868288u    // bf16 P^T lo 112*1536 sh = 86016 fl
#define OFF_KMAT   9954304u    // 150000 (+pad)
#define OFF_COLS   10104320u   // colsP [2][32][128] = 8192 fl
#define OFF_MISC   10113920u   // [3]=Ksum(f) [5]=ctr [8+16b]=barrier slots (b<32)
#define OFF_ZUT    10114688u   // bf16 Zu^T hi 4096*1536 sh = 3145728 fl  (R10 BUG: was sized 1572864)
#define OFF_ZUTL   13260416u   // bf16 Zu^T lo 4096*1536 sh = 3145728 fl -> ends 16406144
#define OFF_AG     16406144u   // warm-start a, 1504 fl (sentinel -1 = cold)
#define OFF_PREVG  16407680u   // warm-start prev rowsums, 1504 fl
#define OFF_BINIT  16409216u   // warm-start b, 128 fl -> end 16409344 fl (~65.6 MB; ws ~268 MB)

#define SINK_BLOCKS 32
#define RPB 47                 // rows per sinkhorn block (32*47 = 1504)
#define PTS 1536               // P^T / ZuT row stride (shorts)
#define CPS 409600u            // CP partial stride (100*4096)

typedef __attribute__((ext_vector_type(8))) short short8_t;
typedef __attribute__((ext_vector_type(4))) float f32x4;

__device__ __forceinline__ short f2bs(float f) {   // fp32 -> bf16 RNE
  unsigned u = __float_as_uint(f);
  unsigned r = (u + 0x7FFFu + ((u >> 16) & 1u)) >> 16;
  return (short)r;
}
__device__ __forceinline__ float bs2f(short s) {
  return __uint_as_float(((unsigned)(unsigned short)s) << 16);
}

// ---------------- preprocessing ----------------
__global__ __launch_bounds__(256) void k_pow_norm(const float* __restrict__ X, float* __restrict__ Z,
                                                  float* __restrict__ msums, unsigned* __restrict__ misc_u,
                                                  float* __restrict__ aG) {
  int i = blockIdx.x, tid = threadIdx.x;
  __shared__ float red[256];
  if (i < 32) msums[i * 256 + tid] = 0.f;
  if (i == 32) { misc_u[tid] = 0u; misc_u[tid + 256] = 0u; misc_u[tid + 512] = 0u; }
  if (i == 33) { for (int z = tid; z < 1504; z += 256) aG[z] = -1.f; }   // cold sentinel
  const float* x = X + (size_t)i * DD;
  float s = 0.f;
  for (int k = tid; k < DD; k += 256) s += x[k] + 1e-6f;
  red[tid] = s; __syncthreads();
  for (int o = 128; o > 0; o >>= 1) { if (tid < o) red[tid] += red[tid + o]; __syncthreads(); }
  float inv = 1.0f / fmaxf(sqrtf(red[0]), 1e-12f);
  float* z = Z + (size_t)i * DD;
  for (int k = tid; k < DD; k += 256) z[k] = sqrtf(x[k] + 1e-6f) * inv;
}

__global__ __launch_bounds__(256) void k_colmeans(const float* __restrict__ Z, float* __restrict__ mLs,
                                                  float* __restrict__ mUs) {
  int k = blockIdx.x * 256 + threadIdx.x;
  int r0 = blockIdx.y * 80;
  float sL = 0.f, sU = 0.f;
  for (int r = r0; r < r0 + 80; ++r) {
    float v = Z[(size_t)r * DD + k];
    if (r < N_L) sL += v; else sU += v;
  }
  if (r0 < N_L) atomicAdd(&mLs[k], sL);
  if (r0 + 80 > N_L) atomicAdd(&mUs[k], sU);
}

__global__ __launch_bounds__(256) void k_center(float* __restrict__ Z, const float* __restrict__ mLs,
                                                const float* __restrict__ mUs) {
  int i = blockIdx.x, tid = threadIdx.x;
  __shared__ float red[256];
  const float* m = (i < N_L) ? mLs : mUs;
  const float scale = (i < N_L) ? (1.0f / 500.0f) : (1.0f / 1500.0f);
  float* z = Z + (size_t)i * DD;
  float s = 0.f;
  for (int k = tid; k < DD; k += 256) { float v = z[k] - m[k] * scale; s += v * v; }
  red[tid] = s; __syncthreads();
  for (int o = 128; o > 0; o >>= 1) { if (tid < o) red[tid] += red[tid + o]; __syncthreads(); }
  float inv = 1.0f / fmaxf(sqrtf(red[0]), 1e-12f);
  for (int k = tid; k < DD; k += 256) z[k] = (z[k] - m[k] * scale) * inv;
}

__global__ __launch_bounds__(256) void k_musinit(const float* __restrict__ Z, float* __restrict__ SL,
                                                 float* __restrict__ mus, short* __restrict__ musb,
                                                 float* __restrict__ musqP, float* __restrict__ binit) {
  int w = blockIdx.x, tid = threadIdx.x;
  __shared__ float red[256];
  if (tid == 0) binit[w] = 1.0f;
  float q = 0.f;
  for (int k = tid; k < DD; k += 256) {
    float s = 0.f;
    for (int sh = 0; sh < SHOT; ++sh) s += Z[(size_t)(sh * WAY + w) * DD + k];
    SL[(size_t)w * DD + k] = s;
    float m = s / 5.0f;
    mus[(size_t)w * DD + k] = m;
    musb[(size_t)w * DD + k] = f2bs(m);
    q += m * m;
  }
  red[tid] = q; __syncthreads();
  for (int o = 128; o > 0; o >>= 1) { if (tid < o) red[tid] += red[tid + o]; __syncthreads(); }
  if (tid == 0) musqP[(size_t)w * 256] = red[0];
  else musqP[(size_t)w * 256 + tid] = 0.f;
}

// ---- one-time: Zu -> bf16 row-major; launched twice (ubase 0 then 768) to sequence overlap ----
__global__ __launch_bounds__(256) void k_zb(const float* __restrict__ Z, short* __restrict__ Zb, int ubase) {
  size_t i0 = (size_t)ubase * DD + ((size_t)blockIdx.x * 256 + threadIdx.x) * 8;
  short8_t v;
  if (i0 < (size_t)N_U * DD) {
    const float* src = Z + (size_t)N_L * DD + i0;
    float4 a = *(const float4*)src;
    float4 b = *(const float4*)(src + 4);
    v[0] = f2bs(a.x); v[1] = f2bs(a.y); v[2] = f2bs(a.z); v[3] = f2bs(a.w);
    v[4] = f2bs(b.x); v[5] = f2bs(b.y); v[6] = f2bs(b.z); v[7] = f2bs(b.w);
  } else {
    v = (short8_t){0, 0, 0, 0, 0, 0, 0, 0};
  }
  *(short8_t*)(Zb + i0) = v;
}

// ---- one-time: Zu^T hi/lo bf16 (4096 x 1536, cols 1500..1535 zeroed) ----
__global__ __launch_bounds__(256) void k_zt(const float* __restrict__ Z, short* __restrict__ ZTH,
                                            short* __restrict__ ZTL) {
  __shared__ float tile[32][33];
  int k0 = blockIdx.x * 32, u0 = blockIdx.y * 32;
  int c = threadIdx.x & 31, r0 = threadIdx.x >> 5;
#pragma unroll
  for (int rr = 0; rr < 4; ++rr) {
    int r = r0 + rr * 8;
    int u = u0 + r;
    tile[r][c] = (u < N_U) ? Z[(size_t)(N_L + u) * DD + k0 + c] : 0.f;
  }
  __syncthreads();
#pragma unroll
  for (int rr = 0; rr < 4; ++rr) {
    int r = r0 + rr * 8;
    float v = tile[c][r];
    short hi = f2bs(v);
    ZTH[(size_t)(k0 + r) * PTS + u0 + c] = hi;
    ZTL[(size_t)(k0 + r) * PTS + u0 + c] = f2bs(v - bs2f(hi));
  }
}

// ---------------- GEMM1+expK fused (MFMA, 4-wave k-split): Kmat[u][w] = exp(-lam*dist) ------------
__global__ __launch_bounds__(256) void k_gemm1K(const short* __restrict__ Zb, const short* __restrict__ musb,
                                                const float* __restrict__ musqP, float* __restrict__ Kmat,
                                                unsigned* __restrict__ misc_u) {
  int tid = threadIdx.x;
  __shared__ float redA[4 * 7 * 4 * 64];   // 28 KB
  __shared__ float musq2[2][128];
  if (blockIdx.x == 0) {
    for (int z = tid; z < 768; z += 256) misc_u[z] = 0u;   // Ksum + barrier slots + ctr
  }
  {
    int w = tid >> 1, half = tid & 1;
    if (w < WAY) {
      const float* mp = musqP + (size_t)w * 256 + half * 128;
      float q = 0.f;
#pragma unroll 4
      for (int bb = 0; bb < 128; bb += 4) {
        float4 v4 = *(const float4*)(mp + bb);
        q += (v4.x + v4.y) + (v4.z + v4.w);
      }
      musq2[half][w] = q;
    }
  }
  int wv = tid >> 6, l = tid & 63;
  int l15 = l & 15, quad = (l >> 4) & 3;
  int u0 = blockIdx.x * 16;
  f32x4 acc[7];
#pragma unroll
  for (int c = 0; c < 7; ++c) acc[c] = (f32x4){0.f, 0.f, 0.f, 0.f};

  const short* bp = Zb + (size_t)(u0 + l15) * DD + wv * 1024 + quad * 8;
  const short* ap = musb + (size_t)l15 * DD + wv * 1024 + quad * 8;
#pragma unroll 2
  for (int kc = 0; kc < 1024; kc += 32) {
    short8_t bf = *(const short8_t*)(bp + kc);
#pragma unroll
    for (int c = 0; c < 7; ++c) {
      short8_t af = *(const short8_t*)(ap + (size_t)c * 16 * DD + kc);
      acc[c] = __builtin_amdgcn_mfma_f32_16x16x32_bf16(af, bf, acc[c], 0, 0, 0);
    }
  }
#pragma unroll
  for (int c = 0; c < 7; ++c)
#pragma unroll
    for (int r = 0; r < 4; ++r)
      redA[((wv * 7 + c) * 4 + r) * 64 + l] = acc[c][r];
  __syncthreads();
  if (wv == 0) {
    int u = u0 + l15;
#pragma unroll
    for (int c = 0; c < 7; ++c)
#pragma unroll
      for (int r = 0; r < 4; ++r) {
        int base = (c * 4 + r) * 64 + l;
        float s = redA[base] + redA[base + 1792] + redA[base + 3584] + redA[base + 5376];
        int w = 16 * c + quad * 4 + r;
        if (w < WAY && u < N_U) {
          float d2 = 1.0f + (musq2[0][w] + musq2[1][w]) - 2.0f * s;
          Kmat[(size_t)u * WAY + w] = expf(-LAMF * sqrtf(fmaxf(d2, 1e-12f)));
        }
      }
  }
}

// ---------------- sinkhorn (32 blocks, symmetric barrier, warm-started a/b/prevs) ----------------
__device__ __forceinline__ void gbar(unsigned* slots, unsigned t) {
  __syncthreads();
  if (threadIdx.x == 0) {
    __threadfence();
    __hip_atomic_store(slots + (unsigned)blockIdx.x * 16, t, __ATOMIC_RELEASE, __HIP_MEMORY_SCOPE_AGENT);
  }
  if (threadIdx.x < SINK_BLOCKS) {
    while (__hip_atomic_load(slots + threadIdx.x * 16, __ATOMIC_ACQUIRE, __HIP_MEMORY_SCOPE_AGENT) < t)
      __builtin_amdgcn_s_sleep(1);
  }
  __syncthreads();
}

__global__ __launch_bounds__(256) void k_sink(const float* __restrict__ Kg,
                                              short* __restrict__ PTH, short* __restrict__ PTL,
                                              float* __restrict__ colsP, float* __restrict__ aG,
                                              float* __restrict__ prevG, float* __restrict__ binit,
                                              unsigned* __restrict__ misc_u, float* __restrict__ misc_f) {
  __shared__ float Kl[RPB * WAY];                // 18.8 KB
  __shared__ float a[RPB], aold[RPB], prevs[RPB], b[WAY];
  __shared__ float rerr[256];
  __shared__ float c2[2 * WAY];
  __shared__ float red[256];
  __shared__ float eSh;
  unsigned* slots = misc_u + 8;
  float* KsumG = misc_f + 3;
  int tid = threadIdx.x;
  int row0 = blockIdx.x * RPB;
  int nrows = (row0 + RPB <= N_U) ? RPB : (N_U - row0);   // last block: 43

  float ks = 0.f;
  for (int idx = tid; idx < nrows * WAY; idx += 256) { float v = Kg[row0 * WAY + idx]; Kl[idx] = v; ks += v; }
  red[tid] = ks; __syncthreads();
  for (int o = 128; o > 0; o >>= 1) { if (tid < o) red[tid] += red[tid + o]; __syncthreads(); }
  if (tid == 0) atomicAdd(KsumG, red[0]);
  if (tid < WAY) b[tid] = binit[tid];        // warm b (1.0 on epoch 0)
  unsigned bt = 1;
  gbar(slots, bt);
  float S = *KsumG;
  bool warm = (aG[row0] >= 0.f);             // -1 sentinel on epoch 0 (deterministic per replay)
  if (tid < RPB) {
    a[tid] = warm ? aG[row0 + tid] : (1.0f / S);   // cold: folds K/K.sum() into a exactly
    prevs[tid] = warm ? prevG[row0 + tid] : 0.f;
  }

  bool conv = false;
  for (int t = 0; t < MAXIT; ++t) {
    float* cp = colsP + (t & 1) * 4096;
    __syncthreads();                       // b stable
    if (tid < nrows) {
      const float* kr = &Kl[tid * WAY];
      float r0 = 0.f, r1 = 0.f, r2 = 0.f, r3 = 0.f;
#pragma unroll 4
      for (int j = 0; j < WAY; j += 4) {
        r0 = fmaf(kr[j], b[j], r0);
        r1 = fmaf(kr[j + 1], b[j + 1], r1);
        r2 = fmaf(kr[j + 2], b[j + 2], r2);
        r3 = fmaf(kr[j + 3], b[j + 3], r3);
      }
      float rs = ((r0 + r1) + (r2 + r3)) * a[tid];
      rerr[tid] = fabsf(prevs[tid] - rs);
      aold[tid] = a[tid];
      a[tid] = a[tid] / rs;                // speculative; rolled back on convergence
      prevs[tid] = rs;
    } else {
      rerr[tid] = 0.f;
    }
    __syncthreads();
    {
      int j = -1, rlo = 0, rhi = 0, slot = 0;
      if (tid < WAY) { j = tid; rlo = 0; rhi = 24; slot = 0; }
      else if (tid >= 128 && tid < 128 + WAY) { j = tid - 128; rlo = 24; rhi = RPB; slot = 1; }
      if (j >= 0) {
        if (rhi > nrows) rhi = nrows;
        float pc = 0.f;
        for (int r = rlo; r < rhi; ++r) pc = fmaf(Kl[r * WAY + j], a[r], pc);
        c2[slot * WAY + j] = pc;
      }
    }
    __syncthreads();
    if (tid < WAY) cp[(unsigned)blockIdx.x * 128 + tid] = c2[tid] + c2[WAY + tid];
    if (tid < 64) {
      float m = fmaxf(fmaxf(rerr[tid], rerr[tid + 64]), fmaxf(rerr[tid + 128], rerr[tid + 192]));
#pragma unroll
      for (int o = 32; o > 0; o >>= 1) m = fmaxf(m, __shfl_down(m, o));
      if (tid == 0) cp[(unsigned)blockIdx.x * 128 + 100] = m;
    }
    ++bt;
    gbar(slots, bt);
    if (tid < 64) {                         // lanes 32..63 contribute 0 (errors >= 0)
      float e = (tid < SINK_BLOCKS) ? cp[tid * 128 + 100] : 0.f;
#pragma unroll
      for (int o = 32; o > 0; o >>= 1) e = fmaxf(e, __shfl_down(e, o));
      if (tid == 0) eSh = e;
    }
    __syncthreads();
    if (eSh <= EPSF) { conv = true; break; }
    if (tid < WAY) {
      float s = 0.f;
#pragma unroll 8
      for (int sb = 0; sb < SINK_BLOCKS; ++sb) s += cp[sb * 128 + tid];
      b[tid] = (float)NQ / s;
    }
  }
  __syncthreads();
  // persist warm-start state for next epoch
  if (tid < nrows) {
    float af = conv ? aold[tid] : a[tid];
    aG[row0 + tid] = af;
    prevG[row0 + tid] = prevs[tid];
  }
  if (blockIdx.x == 0 && tid < WAY) binit[tid] = b[tid];
  // P^T hi/lo bf16 (A-operand for gemm2 + k_final source), coalesced in u
  for (int idx = tid; idx < WAY * nrows; idx += 256) {
    int j = idx / nrows; int r = idx - j * nrows;
    float av = conv ? aold[r] : a[r];
    float p = av * Kl[r * WAY + j] * b[j];
    short hi = f2bs(p);
    PTH[(size_t)j * PTS + row0 + r] = hi;
    PTL[(size_t)j * PTS + row0 + r] = f2bs(p - bs2f(hi));
  }
  if (blockIdx.x == SINK_BLOCKS - 1) {     // zero cols 1500..1503 (gemm2 K loop reads u<1504)
    for (int idx = tid; idx < WAY * 4; idx += 256) {
      int j = idx >> 2;
      PTH[(size_t)j * PTS + 1500 + (idx & 3)] = 0;
      PTL[(size_t)j * PTS + 1500 + (idx & 3)] = 0;
    }
  }
}

// ---------------- GEMM2 (MFMA, 3-term, u-split partials; 2048 waves) ----------------
__global__ __launch_bounds__(64) void k_gemm2(const short* __restrict__ PTH, const short* __restrict__ PTL,
                                              const short* __restrict__ ZTH, const short* __restrict__ ZTL,
                                              float* __restrict__ CPp) {
  int l = threadIdx.x, l15 = l & 15, quad = l >> 4;
  int k0 = blockIdx.x * 16;                      // 256 k-tiles
  int us = blockIdx.y;                           // 8 u-splits
  int kcb = us * 192;
  int kce = (us == 7) ? 1504 : kcb + 192;
  f32x4 acc[7];
#pragma unroll
  for (int c = 0; c < 7; ++c) acc[c] = (f32x4){0.f, 0.f, 0.f, 0.f};
  size_t aoff = (size_t)l15 * PTS + quad * 8;
  const short* bph = ZTH + (size_t)(k0 + l15) * PTS + quad * 8;
  const short* bpl = ZTL + (size_t)(k0 + l15) * PTS + quad * 8;
  for (int kc = kcb; kc < kce; kc += 32) {
    short8_t bh = *(const short8_t*)(bph + kc);
    short8_t bl = *(const short8_t*)(bpl + kc);
#pragma unroll
    for (int c = 0; c < 7; ++c) {
      short8_t ah = *(const short8_t*)(PTH + aoff + (size_t)c * 16 * PTS + kc);
      short8_t al = *(const short8_t*)(PTL + aoff + (size_t)c * 16 * PTS + kc);
      acc[c] = __builtin_amdgcn_mfma_f32_16x16x32_bf16(ah, bh, acc[c], 0, 0, 0);
      acc[c] = __builtin_amdgcn_mfma_f32_16x16x32_bf16(al, bh, acc[c], 0, 0, 0);
      acc[c] = __builtin_amdgcn_mfma_f32_16x16x32_bf16(ah, bl, acc[c], 0, 0, 0);
    }
  }
  float* dst = CPp + (size_t)us * CPS;
#pragma unroll
  for (int c = 0; c < 7; ++c)
#pragma unroll
    for (int r = 0; r < 4; ++r) {
      int w = 16 * c + quad * 4 + r;
      if (w < WAY) dst[(size_t)w * DD + k0 + l15] = acc[c][r];
    }
}

// ---------------- mus update + musq (reduces 8 CP partials; k-split grid (100,4)) ----------------
__global__ __launch_bounds__(256) void k_musup(const float* __restrict__ musR, const float* __restrict__ SL,
                                               const float* __restrict__ CPp, float* __restrict__ musW,
                                               short* __restrict__ musb, float* __restrict__ musqP) {
  int w = blockIdx.x, tid = threadIdx.x;
  int kb = blockIdx.y * 1024;
  __shared__ float red[256];
  float q = 0.f;
  for (int k = kb + tid; k < kb + 1024; k += 256) {
    size_t o = (size_t)w * DD + k;
    float c = 0.f;
#pragma unroll
    for (int s = 0; s < 8; ++s) c += CPp[(size_t)s * CPS + o];
    float emus = (SL[o] + c) / 20.0f;   // p.sum(0) == 5 + 15 exactly
    float m = musR[o];
    float v = m + 0.2f * (emus - m);
    musW[o] = v;
    musb[o] = f2bs(v);
    q += v * v;
  }
  red[tid] = q; __syncthreads();
  for (int o = 128; o > 0; o >>= 1) { if (tid < o) red[tid] += red[tid + o]; __syncthreads(); }
  if (tid == 0) musqP[(size_t)w * 256 + blockIdx.y] = red[0];   // slots 4..255 stay zero (musinit)
}

// ---------------- final logP + acc (P reconstructed from hi+lo) ----------------
__global__ __launch_bounds__(128) void k_final(const short* __restrict__ PTH, const short* __restrict__ PTL,
                                               const int* __restrict__ labels, float* __restrict__ out,
                                               unsigned* __restrict__ ctr) {
  int u = blockIdx.x, tid = threadIdx.x;
  __shared__ float vals[WAY];
  if (tid < WAY) {
    float v = bs2f(PTH[(size_t)tid * PTS + u]) + bs2f(PTL[(size_t)tid * PTS + u]);
    vals[tid] = v;
    out[(size_t)u * WAY + tid] = logf(v + 1e-5f);
  }
  __syncthreads();
  if (tid == 0) {
    int am = 0; float bv = vals[0];
    for (int j = 1; j < WAY; ++j) { if (vals[j] > bv) { bv = vals[j]; am = j; } }
    if (am == labels[N_L + u]) atomicAdd(ctr, 1u);
  }
}

__global__ void k_acc(const unsigned* __restrict__ ctr, float* __restrict__ out) {
  if (threadIdx.x == 0) out[N_U * WAY] = (float)(*ctr) / 1500.0f;
}

// ---------------- host ----------------
extern "C" void kernel_launch(void* const* d_in, const int* in_sizes, int n_in,
                              void* d_out, int out_size, void* d_ws, size_t ws_size,
                              hipStream_t stream) {
  const float* X = (const float*)d_in[0];
  const int* labels = (const int*)d_in[1];
  float* out = (float*)d_out;
  float* ws = (float*)d_ws;

  float* Z     = ws + OFF_Z;
  short* Zb    = (short*)(ws + OFF_Z);       // overlays Z rows 0..768 (sequenced via 2 launches)
  float* CPp   = ws + OFF_CPP;               // dead fp32 Zu region after zb
  float* meanL = ws + OFF_MEANL;
  float* meanU = ws + OFF_MEANU;
  float* SL    = ws + OFF_SL;
  float* musA  = ws + OFF_MUSA;
  float* musB  = ws + OFF_MUSB;
  float* musqP = ws + OFF_MUSQP;
  short* musb16 = (short*)(ws + OFF_MUSB16);
  short* PTH   = (short*)(ws + OFF_PTH);
  short* PTL   = (short*)(ws + OFF_PTL);
  float* Kmat  = ws + OFF_KMAT;
  float* colsP = ws + OFF_COLS;
  float* misc_f = ws + OFF_MISC;
  unsigned* misc_u = (unsigned*)(ws + OFF_MISC);
  short* ZTH   = (short*)(ws + OFF_ZUT);
  short* ZTL   = (short*)(ws + OFF_ZUTL);
  float* aG    = ws + OFF_AG;
  float* prevG = ws + OFF_PREVG;
  float* binit = ws + OFF_BINIT;

  k_pow_norm<<<N_TOT, 256, 0, stream>>>(X, Z, meanL, misc_u, aG);
  k_colmeans<<<dim3(16, 25), 256, 0, stream>>>(Z, meanL, meanU);
  k_center<<<N_TOT, 256, 0, stream>>>(Z, meanL, meanU);
  k_musinit<<<WAY, 256, 0, stream>>>(Z, SL, musA, musb16, musqP, binit);
  k_zt<<<dim3(128, 48), 256, 0, stream>>>(Z, ZTH, ZTL);
  k_zb<<<1536, 256, 0, stream>>>(Z, Zb, 0);    // lo half: no src/dst overlap
  k_zb<<<1536, 256, 0, stream>>>(Z, Zb, 768);  // hi half: overlaps only consumed sources

  float* musR = musA;
  float* musW = musB;
  for (int e = 0; e < 20; ++e) {
    k_gemm1K<<<96, 256, 0, stream>>>(Zb, musb16, musqP, Kmat, misc_u);
    k_sink<<<SINK_BLOCKS, 256, 0, stream>>>(Kmat, PTH, PTL, colsP, aG, prevG, binit, misc_u, misc_f);
    k_gemm2<<<dim3(256, 8), 64, 0, stream>>>(PTH, PTL, ZTH, ZTL, CPp);
    k_musup<<<dim3(WAY, 4), 256, 0, stream>>>(musR, SL, CPp, musW, musb16, musqP);
    float* tmp = musR; musR = musW; musW = tmp;
  }
  k_gemm1K<<<96, 256, 0, stream>>>(Zb, musb16, musqP, Kmat, misc_u);
  k_sink<<<SINK_BLOCKS, 256, 0, stream>>>(Kmat, PTH, PTL, colsP, aG, prevG, binit, misc_u, misc_f);
  k_final<<<N_U, 128, 0, stream>>>(PTH, PTL, labels, out, misc_u + 5);
  k_acc<<<1, 64, 0, stream>>>(misc_u + 5, out);
}